// Round 2
// baseline (485.127 us; speedup 1.0000x reference)
//
#include <hip/hip_runtime.h>
#include <hip/hip_bf16.h>
#include <cstdint>
#include <cstddef>

typedef __attribute__((ext_vector_type(8))) short short8;
typedef __attribute__((ext_vector_type(4))) float f32x4;

#define S_LEN 2048
#define EMB 384
#define NH 6
#define HD 64
#define NB 8

__device__ __forceinline__ unsigned short f2bf(float f) {
  unsigned u = __builtin_bit_cast(unsigned, f);
  u += 0x7fffu + ((u >> 16) & 1u);
  return (unsigned short)(u >> 16);
}

// ---------------- convert x to bf16 ----------------
__global__ __launch_bounds__(256) void k_conv_x(const float* __restrict__ x,
                                                unsigned short* __restrict__ xb,
                                                int n4) {
  int i = blockIdx.x * 256 + threadIdx.x;
  const int stride = gridDim.x * 256;
  for (; i < n4; i += stride) {
    const float4 v = reinterpret_cast<const float4*>(x)[i];
    ushort4 o;
    o.x = f2bf(v.x); o.y = f2bf(v.y); o.z = f2bf(v.z); o.w = f2bf(v.w);
    reinterpret_cast<ushort4*>(xb)[i] = o;
  }
}

// ---------------- transpose + convert weights ----------------
__global__ __launch_bounds__(256) void k_conv_w(
    const float* __restrict__ Wq, const float* __restrict__ Wk,
    const float* __restrict__ Wv, const float* __restrict__ Wo,
    unsigned short* __restrict__ Wqt, unsigned short* __restrict__ Wkt,
    unsigned short* __restrict__ Wvt, unsigned short* __restrict__ Wot) {
  const int idx = blockIdx.x * 256 + threadIdx.x;  // 0 .. 589823
  const int mat = idx / 147456;
  const int rem = idx - mat * 147456;
  const int k = rem / 384;
  const int n = rem - k * 384;
  const float* W = (mat == 0) ? Wq : (mat == 1) ? Wk : (mat == 2) ? Wv : Wo;
  unsigned short* Wt = (mat == 0) ? Wqt : (mat == 1) ? Wkt : (mat == 2) ? Wvt : Wot;
  Wt[n * 384 + k] = f2bf(W[rem]);
}

// ---------------- fused QKV projection GEMM ----------------
// C[m,n] = sum_k xb[m,k] * W[k,n], W given transposed (Wt[n,k]).
// Writes Q/K/V in [B,H,S,D] layout, bf16.
__global__ __launch_bounds__(256) void k_qkv(
    const unsigned short* __restrict__ xb,
    const unsigned short* __restrict__ Wqt,
    const unsigned short* __restrict__ Wkt,
    const unsigned short* __restrict__ Wvt,
    unsigned short* __restrict__ Qb,
    unsigned short* __restrict__ Kb,
    unsigned short* __restrict__ Vb) {
  const int lane = threadIdx.x & 63;
  const int w = threadIdx.x >> 6;
  const int wr = w >> 1, wc = w & 1;
  const int m0 = blockIdx.x * 128 + wr * 64;
  const int wsel = blockIdx.y / 3;
  const int n0 = (blockIdx.y % 3) * 128 + wc * 64;
  const unsigned short* Wt = (wsel == 0) ? Wqt : (wsel == 1) ? Wkt : Wvt;
  unsigned short* Out = (wsel == 0) ? Qb : (wsel == 1) ? Kb : Vb;
  const int lr = lane & 15, lg = lane >> 4;

  f32x4 acc[4][4] = {};
  for (int k = 0; k < EMB; k += 32) {
    short8 a[4], b[4];
#pragma unroll
    for (int ms = 0; ms < 4; ++ms)
      a[ms] = *reinterpret_cast<const short8*>(
          xb + (size_t)(m0 + ms * 16 + lr) * EMB + k + lg * 8);
#pragma unroll
    for (int ns = 0; ns < 4; ++ns)
      b[ns] = *reinterpret_cast<const short8*>(
          Wt + (size_t)(n0 + ns * 16 + lr) * EMB + k + lg * 8);
#pragma unroll
    for (int ms = 0; ms < 4; ++ms)
#pragma unroll
      for (int ns = 0; ns < 4; ++ns)
        acc[ms][ns] = __builtin_amdgcn_mfma_f32_16x16x32_bf16(
            a[ms], b[ns], acc[ms][ns], 0, 0, 0);
  }

#pragma unroll
  for (int ms = 0; ms < 4; ++ms)
#pragma unroll
    for (int ns = 0; ns < 4; ++ns)
#pragma unroll
      for (int r = 0; r < 4; ++r) {
        const int m = m0 + ms * 16 + lg * 4 + r;   // global row = b*S + s
        const int n = n0 + ns * 16 + lr;           // global col = h*D + d
        const int bb = m >> 11;                    // /2048
        const int s = m & 2047;
        const int h = n >> 6;
        const int d = n & 63;
        Out[(((size_t)bb * NH + h) * S_LEN + s) * HD + d] = f2bf(acc[ms][ns][r]);
      }
}

// ---------------- causal flash attention ----------------
// grid: (S/64, B*H); block 256 = 4 waves, wave w handles 16 q-rows.
__global__ __launch_bounds__(256) void k_attn(
    const unsigned short* __restrict__ Qb,
    const unsigned short* __restrict__ Kb,
    const unsigned short* __restrict__ Vb,
    unsigned short* __restrict__ Ob) {
  __shared__ __attribute__((aligned(16))) unsigned short Ks[32 * 72];      // K tile, padded stride 72
  __shared__ __attribute__((aligned(16))) unsigned short Vt[64 * 40];      // V^T tile, padded stride 40
  __shared__ __attribute__((aligned(16))) unsigned short Ps[4 * 16 * 40];  // P per wave, padded stride 40

  const int tid = threadIdx.x;
  const int lane = tid & 63;
  const int w = tid >> 6;
  const int lr = lane & 15, lg = lane >> 4;
  const int qt = blockIdx.x;
  const int bh = blockIdx.y;
  const unsigned short* Qp = Qb + (size_t)bh * S_LEN * HD;
  const unsigned short* Kp = Kb + (size_t)bh * S_LEN * HD;
  const unsigned short* Vp = Vb + (size_t)bh * S_LEN * HD;
  const int qbase = qt * 64 + w * 16;

  const short8 aq0 = *reinterpret_cast<const short8*>(Qp + (qbase + lr) * HD + lg * 8);
  const short8 aq1 = *reinterpret_cast<const short8*>(Qp + (qbase + lr) * HD + 32 + lg * 8);

  f32x4 o[4] = {};
  float m_i[4], l_i[4];
#pragma unroll
  for (int r = 0; r < 4; ++r) { m_i[r] = -1e30f; l_i[r] = 0.f; }

  const int nt = qt * 2 + 2;  // KV tiles of 32, up to causal bound of this q block
  const int srow = tid >> 3;        // 0..31
  const int scol = (tid & 7) * 8;   // 0,8,..,56

  for (int t = 0; t < nt; ++t) {
    __syncthreads();
    // stage K tile [32][64] -> Ks (padded)
    const short8 kv8 = *reinterpret_cast<const short8*>(
        Kp + (size_t)(t * 32 + srow) * HD + scol);
    *reinterpret_cast<short8*>(&Ks[srow * 72 + scol]) = kv8;
    // stage V tile transposed -> Vt[d][kv] (padded)
    const short8 vv8 = *reinterpret_cast<const short8*>(
        Vp + (size_t)(t * 32 + srow) * HD + scol);
#pragma unroll
    for (int j = 0; j < 8; ++j)
      Vt[(scol + j) * 40 + srow] = (unsigned short)vv8[j];
    __syncthreads();

    // scores: S = Q K^T * scale, causal-masked
    float sv[2][4];
#pragma unroll
    for (int ks = 0; ks < 2; ++ks) {
      const short8 bk0 = *reinterpret_cast<const short8*>(&Ks[(ks * 16 + lr) * 72 + lg * 8]);
      const short8 bk1 = *reinterpret_cast<const short8*>(&Ks[(ks * 16 + lr) * 72 + 32 + lg * 8]);
      f32x4 s = {};
      s = __builtin_amdgcn_mfma_f32_16x16x32_bf16(aq0, bk0, s, 0, 0, 0);
      s = __builtin_amdgcn_mfma_f32_16x16x32_bf16(aq1, bk1, s, 0, 0, 0);
      const int kg = t * 32 + ks * 16 + lr;
#pragma unroll
      for (int r = 0; r < 4; ++r) {
        const int qg = qbase + lg * 4 + r;
        const float v = s[r] * 0.125f;
        sv[ks][r] = (kg <= qg) ? v : -1e30f;
      }
    }

    // online softmax per q row (row = 16 lanes of a group, both ksubs)
    float corr[4];
#pragma unroll
    for (int r = 0; r < 4; ++r) {
      float vmax = fmaxf(sv[0][r], sv[1][r]);
      vmax = fmaxf(vmax, __shfl_xor(vmax, 1));
      vmax = fmaxf(vmax, __shfl_xor(vmax, 2));
      vmax = fmaxf(vmax, __shfl_xor(vmax, 4));
      vmax = fmaxf(vmax, __shfl_xor(vmax, 8));
      const float mnew = fmaxf(m_i[r], vmax);
      corr[r] = __expf(m_i[r] - mnew);
      const float p0 = __expf(sv[0][r] - mnew);
      const float p1 = __expf(sv[1][r] - mnew);
      float ps = p0 + p1;
      ps += __shfl_xor(ps, 1);
      ps += __shfl_xor(ps, 2);
      ps += __shfl_xor(ps, 4);
      ps += __shfl_xor(ps, 8);
      l_i[r] = l_i[r] * corr[r] + ps;
      m_i[r] = mnew;
      // P -> LDS (q-local row = lg*4+r, kv col = ks*16+lr)
      Ps[(w * 16 + lg * 4 + r) * 40 + lr] = f2bf(p0);
      Ps[(w * 16 + lg * 4 + r) * 40 + 16 + lr] = f2bf(p1);
    }

    // rescale O accumulator
#pragma unroll
    for (int ns = 0; ns < 4; ++ns)
#pragma unroll
      for (int r = 0; r < 4; ++r)
        o[ns][r] *= corr[r];

    // PV: A = P (from LDS, wave-local), B = V^T tile
    const short8 ap = *reinterpret_cast<const short8*>(&Ps[(w * 16 + lr) * 40 + lg * 8]);
#pragma unroll
    for (int ns = 0; ns < 4; ++ns) {
      const short8 bv = *reinterpret_cast<const short8*>(&Vt[(ns * 16 + lr) * 40 + lg * 8]);
      o[ns] = __builtin_amdgcn_mfma_f32_16x16x32_bf16(ap, bv, o[ns], 0, 0, 0);
    }
  }

  // epilogue: O /= l, write [B,S,E] bf16
  const int b = bh / NH, h = bh - b * NH;
#pragma unroll
  for (int ns = 0; ns < 4; ++ns)
#pragma unroll
    for (int r = 0; r < 4; ++r) {
      const int qg = qbase + lg * 4 + r;
      const float val = o[ns][r] / l_i[r];
      Ob[((size_t)(b * S_LEN + qg)) * EMB + h * HD + ns * 16 + lr] = f2bf(val);
    }
}

// ---------------- output projection: out = O @ Wo + bo (fp32 out) ----------------
__global__ __launch_bounds__(256) void k_oproj(
    const unsigned short* __restrict__ Ob,
    const unsigned short* __restrict__ Wot,
    const float* __restrict__ bo,
    float* __restrict__ out) {
  const int lane = threadIdx.x & 63;
  const int w = threadIdx.x >> 6;
  const int wr = w >> 1, wc = w & 1;
  const int m0 = blockIdx.x * 128 + wr * 64;
  const int n0 = blockIdx.y * 128 + wc * 64;
  const int lr = lane & 15, lg = lane >> 4;

  f32x4 acc[4][4] = {};
  for (int k = 0; k < EMB; k += 32) {
    short8 a[4], b[4];
#pragma unroll
    for (int ms = 0; ms < 4; ++ms)
      a[ms] = *reinterpret_cast<const short8*>(
          Ob + (size_t)(m0 + ms * 16 + lr) * EMB + k + lg * 8);
#pragma unroll
    for (int ns = 0; ns < 4; ++ns)
      b[ns] = *reinterpret_cast<const short8*>(
          Wot + (size_t)(n0 + ns * 16 + lr) * EMB + k + lg * 8);
#pragma unroll
    for (int ms = 0; ms < 4; ++ms)
#pragma unroll
      for (int ns = 0; ns < 4; ++ns)
        acc[ms][ns] = __builtin_amdgcn_mfma_f32_16x16x32_bf16(
            a[ms], b[ns], acc[ms][ns], 0, 0, 0);
  }

#pragma unroll
  for (int ms = 0; ms < 4; ++ms)
#pragma unroll
    for (int ns = 0; ns < 4; ++ns)
#pragma unroll
      for (int r = 0; r < 4; ++r) {
        const int m = m0 + ms * 16 + lg * 4 + r;
        const int n = n0 + ns * 16 + lr;
        out[(size_t)m * EMB + n] = acc[ms][ns][r] + bo[n];
      }
}

// ---------------- launcher ----------------
extern "C" void kernel_launch(void* const* d_in, const int* in_sizes, int n_in,
                              void* d_out, int out_size, void* d_ws, size_t ws_size,
                              hipStream_t stream) {
  const float* x  = (const float*)d_in[0];
  const float* Wq = (const float*)d_in[1];
  const float* Wk = (const float*)d_in[2];
  const float* Wv = (const float*)d_in[3];
  const float* Wo = (const float*)d_in[4];
  const float* bo = (const float*)d_in[5];
  float* out = (float*)d_out;

  uint8_t* ws = (uint8_t*)d_ws;
  // workspace layout (bytes)
  unsigned short* xb  = (unsigned short*)(ws);                 // 16384*384*2 = 12582912
  unsigned short* Wqt = (unsigned short*)(ws + 12582912);      // +294912
  unsigned short* Wkt = (unsigned short*)(ws + 12877824);
  unsigned short* Wvt = (unsigned short*)(ws + 13172736);
  unsigned short* Wot = (unsigned short*)(ws + 13467648);
  unsigned short* Qb  = (unsigned short*)(ws + 13762560);      // +12582912 each
  unsigned short* Kb  = (unsigned short*)(ws + 26345472);
  unsigned short* Vb  = (unsigned short*)(ws + 38928384);
  unsigned short* Ob  = (unsigned short*)(ws + 51511296);      // end 64094208

  hipLaunchKernelGGL(k_conv_x, dim3(1536), dim3(256), 0, stream, x, xb, (NB * S_LEN * EMB) / 4);
  hipLaunchKernelGGL(k_conv_w, dim3(2304), dim3(256), 0, stream, Wq, Wk, Wv, Wo, Wqt, Wkt, Wvt, Wot);
  hipLaunchKernelGGL(k_qkv, dim3(128, 9), dim3(256), 0, stream, xb, Wqt, Wkt, Wvt, Qb, Kb, Vb);
  hipLaunchKernelGGL(k_attn, dim3(S_LEN / 64, NB * NH), dim3(256), 0, stream, Qb, Kb, Vb, Ob);
  hipLaunchKernelGGL(k_oproj, dim3(128, 3), dim3(256), 0, stream, Ob, Wot, bo, out);
}

// Round 3
// 277.052 us; speedup vs baseline: 1.7510x; 1.7510x over previous
//
#include <hip/hip_runtime.h>
#include <hip/hip_bf16.h>
#include <cstdint>
#include <cstddef>

typedef __attribute__((ext_vector_type(8))) short short8;
typedef __attribute__((ext_vector_type(4))) float f32x4;

#define S_LEN 2048
#define EMB 384
#define NH 6
#define HD 64
#define NB 8

__device__ __forceinline__ unsigned short f2bf(float f) {
  unsigned u = __builtin_bit_cast(unsigned, f);
  u += 0x7fffu + ((u >> 16) & 1u);
  return (unsigned short)(u >> 16);
}

// ---------------- convert x to bf16 ----------------
__global__ __launch_bounds__(256) void k_conv_x(const float* __restrict__ x,
                                                unsigned short* __restrict__ xb,
                                                int n4) {
  int i = blockIdx.x * 256 + threadIdx.x;
  const int stride = gridDim.x * 256;
  for (; i < n4; i += stride) {
    const float4 v = reinterpret_cast<const float4*>(x)[i];
    ushort4 o;
    o.x = f2bf(v.x); o.y = f2bf(v.y); o.z = f2bf(v.z); o.w = f2bf(v.w);
    reinterpret_cast<ushort4*>(xb)[i] = o;
  }
}

// ---------------- transpose + convert weights ----------------
__global__ __launch_bounds__(256) void k_conv_w(
    const float* __restrict__ Wq, const float* __restrict__ Wk,
    const float* __restrict__ Wv, const float* __restrict__ Wo,
    unsigned short* __restrict__ Wqt, unsigned short* __restrict__ Wkt,
    unsigned short* __restrict__ Wvt, unsigned short* __restrict__ Wot) {
  const int idx = blockIdx.x * 256 + threadIdx.x;  // 0 .. 589823
  const int mat = idx / 147456;
  const int rem = idx - mat * 147456;
  const int k = rem / 384;
  const int n = rem - k * 384;
  const float* W = (mat == 0) ? Wq : (mat == 1) ? Wk : (mat == 2) ? Wv : Wo;
  unsigned short* Wt = (mat == 0) ? Wqt : (mat == 1) ? Wkt : (mat == 2) ? Wvt : Wot;
  Wt[n * 384 + k] = f2bf(W[rem]);
}

// ---------------- fused QKV projection GEMM ----------------
__global__ __launch_bounds__(256) void k_qkv(
    const unsigned short* __restrict__ xb,
    const unsigned short* __restrict__ Wqt,
    const unsigned short* __restrict__ Wkt,
    const unsigned short* __restrict__ Wvt,
    unsigned short* __restrict__ Qb,
    unsigned short* __restrict__ Kb,
    unsigned short* __restrict__ Vb) {
  const int lane = threadIdx.x & 63;
  const int w = threadIdx.x >> 6;
  const int wr = w >> 1, wc = w & 1;
  const int m0 = blockIdx.x * 128 + wr * 64;
  const int wsel = blockIdx.y / 3;
  const int n0 = (blockIdx.y % 3) * 128 + wc * 64;
  const unsigned short* Wt = (wsel == 0) ? Wqt : (wsel == 1) ? Wkt : Wvt;
  unsigned short* Out = (wsel == 0) ? Qb : (wsel == 1) ? Kb : Vb;
  const int lr = lane & 15, lg = lane >> 4;

  f32x4 acc[4][4] = {};
  for (int k = 0; k < EMB; k += 32) {
    short8 a[4], b[4];
#pragma unroll
    for (int ms = 0; ms < 4; ++ms)
      a[ms] = *reinterpret_cast<const short8*>(
          xb + (size_t)(m0 + ms * 16 + lr) * EMB + k + lg * 8);
#pragma unroll
    for (int ns = 0; ns < 4; ++ns)
      b[ns] = *reinterpret_cast<const short8*>(
          Wt + (size_t)(n0 + ns * 16 + lr) * EMB + k + lg * 8);
#pragma unroll
    for (int ms = 0; ms < 4; ++ms)
#pragma unroll
      for (int ns = 0; ns < 4; ++ns)
        acc[ms][ns] = __builtin_amdgcn_mfma_f32_16x16x32_bf16(
            a[ms], b[ns], acc[ms][ns], 0, 0, 0);
  }

#pragma unroll
  for (int ms = 0; ms < 4; ++ms)
#pragma unroll
    for (int ns = 0; ns < 4; ++ns)
#pragma unroll
      for (int r = 0; r < 4; ++r) {
        const int m = m0 + ms * 16 + lg * 4 + r;   // b*S + s
        const int n = n0 + ns * 16 + lr;           // h*D + d
        const int bb = m >> 11;
        const int s = m & 2047;
        const int h = n >> 6;
        const int d = n & 63;
        Out[(((size_t)bb * NH + h) * S_LEN + s) * HD + d] = f2bf(acc[ms][ns][r]);
      }
}

// ---------------- V transpose: [b,h,s,d] -> [b,h,d,s] ----------------
// stride-65 LDS: both scatter phases bank-conflict-free.
__global__ __launch_bounds__(256) void k_vt(const unsigned short* __restrict__ Vb,
                                            unsigned short* __restrict__ Vtg) {
  __shared__ unsigned short L[64 * 65];
  const int tid = threadIdx.x;
  const int g = tid & 7;        // 16B chunk
  const int h = tid >> 3;       // 0..31
  const int st = blockIdx.x;    // s tile
  const int bh = blockIdx.y;
  const unsigned short* src = Vb + (size_t)bh * S_LEN * HD + (size_t)st * 64 * HD;
  unsigned short* dst = Vtg + (size_t)bh * S_LEN * HD;

#pragma unroll
  for (int c = 0; c < 2; ++c) {
    const int s = h + 32 * c;
    const short8 v = *reinterpret_cast<const short8*>(src + s * HD + g * 8);
#pragma unroll
    for (int j = 0; j < 8; ++j) L[s * 65 + g * 8 + j] = (unsigned short)v[j];
  }
  __syncthreads();
#pragma unroll
  for (int c = 0; c < 2; ++c) {
    const int d = h + 32 * c;
    short8 v;
#pragma unroll
    for (int j = 0; j < 8; ++j) v[j] = (short)L[(g * 8 + j) * 65 + d];
    *reinterpret_cast<short8*>(dst + (size_t)d * S_LEN + st * 64 + g * 8) = v;
  }
}

// ---------------- causal flash attention ----------------
// grid: (16 pairs, B*H); block 256 = 4 waves x 16 q-rows; KV tile 64.
// block handles q-tiles {pair, 31-pair}: exactly 33 KV tiles each -> balanced.
__global__ __launch_bounds__(256) void k_attn(
    const unsigned short* __restrict__ Qb,
    const unsigned short* __restrict__ Kb,
    const unsigned short* __restrict__ Vtg,
    unsigned short* __restrict__ Ob) {
  __shared__ __attribute__((aligned(16))) unsigned short Ks[64 * 72];   // K tile [kv][d]
  __shared__ __attribute__((aligned(16))) unsigned short Vt[64 * 72];   // V^T tile [d][kv]
  __shared__ __attribute__((aligned(16))) unsigned short Ps[4 * 16 * 72]; // P per wave [q][kv]

  const int tid = threadIdx.x;
  const int lane = tid & 63;
  const int w = tid >> 6;
  const int lr = lane & 15, lg = lane >> 4;
  const int pair = blockIdx.x;
  const int bh = blockIdx.y;
  const unsigned short* Qp = Qb + (size_t)bh * S_LEN * HD;
  const unsigned short* Kp = Kb + (size_t)bh * S_LEN * HD;
  const unsigned short* Vp = Vtg + (size_t)bh * S_LEN * HD;
  const int b = bh / NH, hh = bh - b * NH;

  const int srow = tid >> 3;        // 0..31
  const int scol = (tid & 7) * 8;   // 0..56

  for (int phase = 0; phase < 2; ++phase) {
    const int qt = phase ? (31 - pair) : pair;
    const int qbase = qt * 64 + w * 16;

    const short8 aq0 = *reinterpret_cast<const short8*>(Qp + (size_t)(qbase + lr) * HD + lg * 8);
    const short8 aq1 = *reinterpret_cast<const short8*>(Qp + (size_t)(qbase + lr) * HD + 32 + lg * 8);

    f32x4 o[4] = {};
    float m_i[4], l_i[4];
#pragma unroll
    for (int r = 0; r < 4; ++r) { m_i[r] = -1e30f; l_i[r] = 0.f; }

    // prefetch tile 0
    short8 pk0 = *reinterpret_cast<const short8*>(Kp + (size_t)srow * HD + scol);
    short8 pk1 = *reinterpret_cast<const short8*>(Kp + (size_t)(srow + 32) * HD + scol);
    short8 pv0 = *reinterpret_cast<const short8*>(Vp + (size_t)srow * S_LEN + scol);
    short8 pv1 = *reinterpret_cast<const short8*>(Vp + (size_t)(srow + 32) * S_LEN + scol);

    for (int t = 0; t <= qt; ++t) {
      __syncthreads();
      *reinterpret_cast<short8*>(&Ks[srow * 72 + scol]) = pk0;
      *reinterpret_cast<short8*>(&Ks[(srow + 32) * 72 + scol]) = pk1;
      *reinterpret_cast<short8*>(&Vt[srow * 72 + scol]) = pv0;
      *reinterpret_cast<short8*>(&Vt[(srow + 32) * 72 + scol]) = pv1;
      __syncthreads();

      if (t < qt) {  // prefetch next tile under compute
        const int tn = t + 1;
        pk0 = *reinterpret_cast<const short8*>(Kp + (size_t)(tn * 64 + srow) * HD + scol);
        pk1 = *reinterpret_cast<const short8*>(Kp + (size_t)(tn * 64 + srow + 32) * HD + scol);
        pv0 = *reinterpret_cast<const short8*>(Vp + (size_t)srow * S_LEN + tn * 64 + scol);
        pv1 = *reinterpret_cast<const short8*>(Vp + (size_t)(srow + 32) * S_LEN + tn * 64 + scol);
      }

      const bool diag = (t == qt);
      float sv[4][4];
#pragma unroll
      for (int ks = 0; ks < 4; ++ks) {
        if (diag && ks > w) {
#pragma unroll
          for (int r = 0; r < 4; ++r) sv[ks][r] = -1e30f;
        } else {
          const short8 bk0 = *reinterpret_cast<const short8*>(&Ks[(ks * 16 + lr) * 72 + lg * 8]);
          const short8 bk1 = *reinterpret_cast<const short8*>(&Ks[(ks * 16 + lr) * 72 + 32 + lg * 8]);
          f32x4 s = {};
          s = __builtin_amdgcn_mfma_f32_16x16x32_bf16(aq0, bk0, s, 0, 0, 0);
          s = __builtin_amdgcn_mfma_f32_16x16x32_bf16(aq1, bk1, s, 0, 0, 0);
          if (diag && ks == w) {
#pragma unroll
            for (int r = 0; r < 4; ++r)
              sv[ks][r] = (lr <= lg * 4 + r) ? s[r] * 0.125f : -1e30f;
          } else {
#pragma unroll
            for (int r = 0; r < 4; ++r) sv[ks][r] = s[r] * 0.125f;
          }
        }
      }

      // online softmax per q row (row spread over 16 lr lanes x 4 ks)
      float corr[4];
#pragma unroll
      for (int r = 0; r < 4; ++r) {
        float vmax = fmaxf(fmaxf(sv[0][r], sv[1][r]), fmaxf(sv[2][r], sv[3][r]));
        vmax = fmaxf(vmax, __shfl_xor(vmax, 1));
        vmax = fmaxf(vmax, __shfl_xor(vmax, 2));
        vmax = fmaxf(vmax, __shfl_xor(vmax, 4));
        vmax = fmaxf(vmax, __shfl_xor(vmax, 8));
        const float mnew = fmaxf(m_i[r], vmax);
        corr[r] = __expf(m_i[r] - mnew);
        float p[4], ps = 0.f;
#pragma unroll
        for (int ks = 0; ks < 4; ++ks) { p[ks] = __expf(sv[ks][r] - mnew); ps += p[ks]; }
        ps += __shfl_xor(ps, 1);
        ps += __shfl_xor(ps, 2);
        ps += __shfl_xor(ps, 4);
        ps += __shfl_xor(ps, 8);
        l_i[r] = l_i[r] * corr[r] + ps;
        m_i[r] = mnew;
        const int prow = (w * 16 + lg * 4 + r) * 72;
#pragma unroll
        for (int ks = 0; ks < 4; ++ks) Ps[prow + ks * 16 + lr] = f2bf(p[ks]);
      }

#pragma unroll
      for (int ns = 0; ns < 4; ++ns)
#pragma unroll
        for (int r = 0; r < 4; ++r) o[ns][r] *= corr[r];

      // PV: A = P[q][kv] (wave-local), B = V^T[d][kv]
      const short8 ap0 = *reinterpret_cast<const short8*>(&Ps[(w * 16 + lr) * 72 + lg * 8]);
      const short8 ap1 = *reinterpret_cast<const short8*>(&Ps[(w * 16 + lr) * 72 + 32 + lg * 8]);
#pragma unroll
      for (int ns = 0; ns < 4; ++ns) {
        const short8 bv0 = *reinterpret_cast<const short8*>(&Vt[(ns * 16 + lr) * 72 + lg * 8]);
        const short8 bv1 = *reinterpret_cast<const short8*>(&Vt[(ns * 16 + lr) * 72 + 32 + lg * 8]);
        o[ns] = __builtin_amdgcn_mfma_f32_16x16x32_bf16(ap0, bv0, o[ns], 0, 0, 0);
        o[ns] = __builtin_amdgcn_mfma_f32_16x16x32_bf16(ap1, bv1, o[ns], 0, 0, 0);
      }
    }

    // epilogue
#pragma unroll
    for (int ns = 0; ns < 4; ++ns)
#pragma unroll
      for (int r = 0; r < 4; ++r) {
        const int qg = qbase + lg * 4 + r;
        const float val = o[ns][r] / l_i[r];
        Ob[((size_t)(b * S_LEN + qg)) * EMB + hh * HD + ns * 16 + lr] = f2bf(val);
      }
  }
}

// ---------------- output projection ----------------
__global__ __launch_bounds__(256) void k_oproj(
    const unsigned short* __restrict__ Ob,
    const unsigned short* __restrict__ Wot,
    const float* __restrict__ bo,
    float* __restrict__ out) {
  const int lane = threadIdx.x & 63;
  const int w = threadIdx.x >> 6;
  const int wr = w >> 1, wc = w & 1;
  const int m0 = blockIdx.x * 128 + wr * 64;
  const int n0 = blockIdx.y * 128 + wc * 64;
  const int lr = lane & 15, lg = lane >> 4;

  f32x4 acc[4][4] = {};
  for (int k = 0; k < EMB; k += 32) {
    short8 a[4], b[4];
#pragma unroll
    for (int ms = 0; ms < 4; ++ms)
      a[ms] = *reinterpret_cast<const short8*>(
          Ob + (size_t)(m0 + ms * 16 + lr) * EMB + k + lg * 8);
#pragma unroll
    for (int ns = 0; ns < 4; ++ns)
      b[ns] = *reinterpret_cast<const short8*>(
          Wot + (size_t)(n0 + ns * 16 + lr) * EMB + k + lg * 8);
#pragma unroll
    for (int ms = 0; ms < 4; ++ms)
#pragma unroll
      for (int ns = 0; ns < 4; ++ns)
        acc[ms][ns] = __builtin_amdgcn_mfma_f32_16x16x32_bf16(
            a[ms], b[ns], acc[ms][ns], 0, 0, 0);
  }

#pragma unroll
  for (int ms = 0; ms < 4; ++ms)
#pragma unroll
    for (int ns = 0; ns < 4; ++ns)
#pragma unroll
      for (int r = 0; r < 4; ++r) {
        const int m = m0 + ms * 16 + lg * 4 + r;
        const int n = n0 + ns * 16 + lr;
        out[(size_t)m * EMB + n] = acc[ms][ns][r] + bo[n];
      }
}

// ---------------- launcher ----------------
extern "C" void kernel_launch(void* const* d_in, const int* in_sizes, int n_in,
                              void* d_out, int out_size, void* d_ws, size_t ws_size,
                              hipStream_t stream) {
  const float* x  = (const float*)d_in[0];
  const float* Wq = (const float*)d_in[1];
  const float* Wk = (const float*)d_in[2];
  const float* Wv = (const float*)d_in[3];
  const float* Wo = (const float*)d_in[4];
  const float* bo = (const float*)d_in[5];
  float* out = (float*)d_out;

  uint8_t* ws = (uint8_t*)d_ws;
  unsigned short* xb  = (unsigned short*)(ws);                 // 12582912 B
  unsigned short* Wqt = (unsigned short*)(ws + 12582912);
  unsigned short* Wkt = (unsigned short*)(ws + 12877824);
  unsigned short* Wvt = (unsigned short*)(ws + 13172736);
  unsigned short* Wot = (unsigned short*)(ws + 13467648);
  unsigned short* Qb  = (unsigned short*)(ws + 13762560);
  unsigned short* Kb  = (unsigned short*)(ws + 26345472);
  unsigned short* Vb  = (unsigned short*)(ws + 38928384);
  unsigned short* Ob  = (unsigned short*)(ws + 51511296);      // end 64094208
  unsigned short* Vtg = xb;  // xb dead after k_qkv; reuse for V^T (same 12.58MB)

  hipLaunchKernelGGL(k_conv_x, dim3(1536), dim3(256), 0, stream, x, xb, (NB * S_LEN * EMB) / 4);
  hipLaunchKernelGGL(k_conv_w, dim3(2304), dim3(256), 0, stream, Wq, Wk, Wv, Wo, Wqt, Wkt, Wvt, Wot);
  hipLaunchKernelGGL(k_qkv, dim3(128, 9), dim3(256), 0, stream, xb, Wqt, Wkt, Wvt, Qb, Kb, Vb);
  hipLaunchKernelGGL(k_vt, dim3(S_LEN / 64, NB * NH), dim3(256), 0, stream, Vb, Vtg);
  hipLaunchKernelGGL(k_attn, dim3(16, NB * NH), dim3(256), 0, stream, Qb, Kb, Vtg, Ob);
  hipLaunchKernelGGL(k_oproj, dim3(128, 3), dim3(256), 0, stream, Ob, Wot, bo, out);
}

// Round 4
// 265.273 us; speedup vs baseline: 1.8288x; 1.0444x over previous
//
#include <hip/hip_runtime.h>
#include <hip/hip_bf16.h>
#include <cstdint>
#include <cstddef>

typedef __attribute__((ext_vector_type(8))) short short8;
typedef __attribute__((ext_vector_type(4))) float f32x4;

#define S_LEN 2048
#define EMB 384
#define NH 6
#define HD 64
#define NB 8
// Q pre-scale: (1/sqrt(64)) * log2(e) so attn uses exp2 directly
#define QSCALE 0.180336880f

__device__ __forceinline__ unsigned short f2bf(float f) {
  unsigned u = __builtin_bit_cast(unsigned, f);
  u += 0x7fffu + ((u >> 16) & 1u);
  return (unsigned short)(u >> 16);
}

// ---------------- prep: x->bf16 and weight transpose+convert (fused) ----------------
__global__ __launch_bounds__(256) void k_prep(
    const float* __restrict__ x, unsigned short* __restrict__ xb,
    const float* __restrict__ Wq, const float* __restrict__ Wk,
    const float* __restrict__ Wv, const float* __restrict__ Wo,
    unsigned short* __restrict__ Wqt, unsigned short* __restrict__ Wkt,
    unsigned short* __restrict__ Wvt, unsigned short* __restrict__ Wot) {
  const int tid = threadIdx.x;
  if (blockIdx.x < 1536) {
    // x convert: 1572864 float4 items over 1536 blocks (4 iters each)
    int i = blockIdx.x * 256 + tid;
    const int n4 = (NB * S_LEN * EMB) / 4;
    for (; i < n4; i += 1536 * 256) {
      const float4 v = reinterpret_cast<const float4*>(x)[i];
      ushort4 o;
      o.x = f2bf(v.x); o.y = f2bf(v.y); o.z = f2bf(v.z); o.w = f2bf(v.w);
      reinterpret_cast<ushort4*>(xb)[i] = o;
    }
  } else {
    const int idx = (blockIdx.x - 1536) * 256 + tid;  // 0..589823
    const int mat = idx / 147456;
    const int rem = idx - mat * 147456;
    const int k = rem / 384;
    const int n = rem - k * 384;
    const float* W = (mat == 0) ? Wq : (mat == 1) ? Wk : (mat == 2) ? Wv : Wo;
    unsigned short* Wt = (mat == 0) ? Wqt : (mat == 1) ? Wkt : (mat == 2) ? Wvt : Wot;
    Wt[n * 384 + k] = f2bf(W[rem]);
  }
}

// ---------------- fused QKV projection GEMM (LDS-staged A) ----------------
// grid (128, 9): y = wsel*3 + ngrp. Writes Q (pre-scaled) / K as [b,h,s,d], V as [b,h,d,s].
__global__ __launch_bounds__(256) void k_qkv(
    const unsigned short* __restrict__ xb,
    const unsigned short* __restrict__ Wqt,
    const unsigned short* __restrict__ Wkt,
    const unsigned short* __restrict__ Wvt,
    unsigned short* __restrict__ Qb,
    unsigned short* __restrict__ Kb,
    unsigned short* __restrict__ Vtb) {
  __shared__ __attribute__((aligned(16))) unsigned short La[128 * 72];  // A k-tile, pad 72

  const int tid = threadIdx.x;
  const int lane = tid & 63;
  const int w = tid >> 6;
  const int wr = w >> 1, wc = w & 1;
  const int lr = lane & 15, lg = lane >> 4;
  const int m0 = blockIdx.x * 128;
  const int wsel = blockIdx.y / 3;
  const int n0 = (blockIdx.y % 3) * 128;
  const unsigned short* Wt = (wsel == 0) ? Wqt : (wsel == 1) ? Wkt : Wvt;

  const int srow = tid >> 3;       // 0..31
  const int sg = tid & 7;          // 16B slot

  f32x4 acc[4][4] = {};
  short8 st[4];
#pragma unroll
  for (int i = 0; i < 4; ++i)
    st[i] = *reinterpret_cast<const short8*>(
        xb + (size_t)(m0 + i * 32 + srow) * EMB + sg * 8);

  for (int kt = 0; kt < 6; ++kt) {
    __syncthreads();
#pragma unroll
    for (int i = 0; i < 4; ++i)
      *reinterpret_cast<short8*>(&La[(i * 32 + srow) * 72 + sg * 8]) = st[i];
    __syncthreads();
    if (kt < 5) {
      const int kn = (kt + 1) * 64;
#pragma unroll
      for (int i = 0; i < 4; ++i)
        st[i] = *reinterpret_cast<const short8*>(
            xb + (size_t)(m0 + i * 32 + srow) * EMB + kn + sg * 8);
    }
#pragma unroll
    for (int kk = 0; kk < 2; ++kk) {
      short8 a[4], b[4];
#pragma unroll
      for (int ms = 0; ms < 4; ++ms)
        a[ms] = *reinterpret_cast<const short8*>(
            &La[(wr * 64 + ms * 16 + lr) * 72 + kk * 32 + lg * 8]);
#pragma unroll
      for (int ns = 0; ns < 4; ++ns)
        b[ns] = *reinterpret_cast<const short8*>(
            Wt + (size_t)(n0 + wc * 64 + ns * 16 + lr) * EMB + kt * 64 + kk * 32 + lg * 8);
#pragma unroll
      for (int ms = 0; ms < 4; ++ms)
#pragma unroll
        for (int ns = 0; ns < 4; ++ns)
          acc[ms][ns] = __builtin_amdgcn_mfma_f32_16x16x32_bf16(
              a[ms], b[ns], acc[ms][ns], 0, 0, 0);
    }
  }

  const float sc = (wsel == 0) ? QSCALE : 1.0f;
#pragma unroll
  for (int ms = 0; ms < 4; ++ms)
#pragma unroll
    for (int ns = 0; ns < 4; ++ns)
#pragma unroll
      for (int r = 0; r < 4; ++r) {
        const int m = m0 + wr * 64 + ms * 16 + lg * 4 + r;  // b*S + s
        const int n = n0 + wc * 64 + ns * 16 + lr;          // h*D + d
        const int bb = m >> 11;
        const int s = m & 2047;
        const int h = n >> 6;
        const int d = n & 63;
        const unsigned short v = f2bf(acc[ms][ns][r] * sc);
        if (wsel == 2)  // V stored transposed [b,h,d,s]
          Vtb[(((size_t)bb * NH + h) * HD + d) * S_LEN + s] = v;
        else if (wsel == 0)
          Qb[(((size_t)bb * NH + h) * S_LEN + s) * HD + d] = v;
        else
          Kb[(((size_t)bb * NH + h) * S_LEN + s) * HD + d] = v;
      }
}

// ---------------- causal flash attention (KVBLK=128) ----------------
// grid 768 linear-swizzled; block 256 = 4 waves x 16 q-rows; q-tile 64.
__global__ __launch_bounds__(256) void k_attn(
    const unsigned short* __restrict__ Qb,
    const unsigned short* __restrict__ Kb,
    const unsigned short* __restrict__ Vtg,
    unsigned short* __restrict__ Ob) {
  __shared__ __attribute__((aligned(16))) unsigned short Ks[128 * 72];   // K [kv][d] pad72
  __shared__ __attribute__((aligned(16))) unsigned short Vt[64 * 136];   // V^T [d][kv] pad136
  __shared__ __attribute__((aligned(16))) unsigned short Ps[64 * 136];   // P [q][kv] pad136, XOR-swz

  const int tid = threadIdx.x;
  const int lane = tid & 63;
  const int w = tid >> 6;
  const int lr = lane & 15, lg = lane >> 4;

  // XCD-aware swizzle: 768 blocks, 8 XCDs, 96 per XCD; 16 consecutive = one bh
  const int lin = blockIdx.y * 16 + blockIdx.x;
  const int swz = (lin & 7) * 96 + (lin >> 3);
  const int pair = swz & 15;
  const int bh = swz >> 4;

  const unsigned short* Qp = Qb + (size_t)bh * S_LEN * HD;
  const unsigned short* Kp = Kb + (size_t)bh * S_LEN * HD;
  const unsigned short* Vp = Vtg + (size_t)bh * S_LEN * HD;
  const int b = bh / NH, hh = bh - b * NH;

  const int krow = tid >> 3;       // 0..31 (K staging)
  const int kg8 = (tid & 7) * 8;
  const int vrow = tid >> 4;       // 0..15 (V staging)
  const int vg8 = (tid & 15) * 8;

  for (int phase = 0; phase < 2; ++phase) {
    const int qt = phase ? (31 - pair) : pair;
    const int qbase = qt * 64 + w * 16;
    const int nt = (qt + 2) >> 1;  // KV tiles of 128

    const short8 aq0 = *reinterpret_cast<const short8*>(Qp + (size_t)(qbase + lr) * HD + lg * 8);
    const short8 aq1 = *reinterpret_cast<const short8*>(Qp + (size_t)(qbase + lr) * HD + 32 + lg * 8);

    f32x4 o[4] = {};
    float m_i[4], l_i[4];
#pragma unroll
    for (int r = 0; r < 4; ++r) { m_i[r] = -1e30f; l_i[r] = 0.f; }

    short8 pk[4], pv[4];
#pragma unroll
    for (int i = 0; i < 4; ++i) {
      pk[i] = *reinterpret_cast<const short8*>(Kp + (size_t)(i * 32 + krow) * HD + kg8);
      pv[i] = *reinterpret_cast<const short8*>(Vp + (size_t)(i * 16 + vrow) * S_LEN + vg8);
    }

    for (int t = 0; t < nt; ++t) {
      __syncthreads();
#pragma unroll
      for (int i = 0; i < 4; ++i) {
        *reinterpret_cast<short8*>(&Ks[(i * 32 + krow) * 72 + kg8]) = pk[i];
        *reinterpret_cast<short8*>(&Vt[(i * 16 + vrow) * 136 + vg8]) = pv[i];
      }
      __syncthreads();
      if (t + 1 < nt) {
        const int tn = (t + 1) * 128;
#pragma unroll
        for (int i = 0; i < 4; ++i) {
          pk[i] = *reinterpret_cast<const short8*>(Kp + (size_t)(tn + i * 32 + krow) * HD + kg8);
          pv[i] = *reinterpret_cast<const short8*>(Vp + (size_t)(i * 16 + vrow) * S_LEN + tn + vg8);
        }
      }

      float sv[8][4];
#pragma unroll
      for (int ks = 0; ks < 8; ++ks) {
        const int kstart = t * 128 + ks * 16;
        if (kstart > qbase + 15) {
#pragma unroll
          for (int r = 0; r < 4; ++r) sv[ks][r] = -1e30f;
        } else {
          const short8 bk0 = *reinterpret_cast<const short8*>(&Ks[(ks * 16 + lr) * 72 + lg * 8]);
          const short8 bk1 = *reinterpret_cast<const short8*>(&Ks[(ks * 16 + lr) * 72 + 32 + lg * 8]);
          f32x4 s = {};
          s = __builtin_amdgcn_mfma_f32_16x16x32_bf16(aq0, bk0, s, 0, 0, 0);
          s = __builtin_amdgcn_mfma_f32_16x16x32_bf16(aq1, bk1, s, 0, 0, 0);
          if (kstart + 15 <= qbase) {
#pragma unroll
            for (int r = 0; r < 4; ++r) sv[ks][r] = s[r];
          } else {
            const int kg = kstart + lr;
#pragma unroll
            for (int r = 0; r < 4; ++r)
              sv[ks][r] = (kg <= qbase + lg * 4 + r) ? s[r] : -1e30f;
          }
        }
      }

      // online softmax (base-2; Q pre-scaled by 0.125*log2e)
      float corr[4];
#pragma unroll
      for (int r = 0; r < 4; ++r) {
        float vmax = sv[0][r];
#pragma unroll
        for (int ks = 1; ks < 8; ++ks) vmax = fmaxf(vmax, sv[ks][r]);
        vmax = fmaxf(vmax, __shfl_xor(vmax, 1));
        vmax = fmaxf(vmax, __shfl_xor(vmax, 2));
        vmax = fmaxf(vmax, __shfl_xor(vmax, 4));
        vmax = fmaxf(vmax, __shfl_xor(vmax, 8));
        const float mnew = fmaxf(m_i[r], vmax);
        corr[r] = __builtin_amdgcn_exp2f(m_i[r] - mnew);
        float p[8], ps = 0.f;
#pragma unroll
        for (int ks = 0; ks < 8; ++ks) { p[ks] = __builtin_amdgcn_exp2f(sv[ks][r] - mnew); ps += p[ks]; }
        ps += __shfl_xor(ps, 1);
        ps += __shfl_xor(ps, 2);
        ps += __shfl_xor(ps, 4);
        ps += __shfl_xor(ps, 8);
        l_i[r] = l_i[r] * corr[r] + ps;
        m_i[r] = mnew;
        const int q = w * 16 + lg * 4 + r;
        const int xr = ((q >> 3) & 1) << 4;  // XOR-swizzle: kills 4-way store conflict
        const int prow = q * 136;
#pragma unroll
        for (int ks = 0; ks < 8; ++ks) Ps[prow + ((ks * 16 + lr) ^ xr)] = f2bf(p[ks]);
      }

#pragma unroll
      for (int ns = 0; ns < 4; ++ns)
#pragma unroll
        for (int r = 0; r < 4; ++r) o[ns][r] *= corr[r];

      // PV: A = P[q][kv] (wave-local rows, XOR-swz), B = V^T[d][kv]
      const int q2 = (w * 16 + lr) * 136;
      const int xr2 = ((lr >> 3) & 1) << 4;
#pragma unroll
      for (int kk = 0; kk < 4; ++kk) {
        const short8 ap = *reinterpret_cast<const short8*>(&Ps[q2 + ((kk * 32 + lg * 8) ^ xr2)]);
#pragma unroll
        for (int ns = 0; ns < 4; ++ns) {
          const short8 bv = *reinterpret_cast<const short8*>(&Vt[(ns * 16 + lr) * 136 + kk * 32 + lg * 8]);
          o[ns] = __builtin_amdgcn_mfma_f32_16x16x32_bf16(ap, bv, o[ns], 0, 0, 0);
        }
      }
    }

    // epilogue
#pragma unroll
    for (int ns = 0; ns < 4; ++ns)
#pragma unroll
      for (int r = 0; r < 4; ++r) {
        const int qg = qbase + lg * 4 + r;
        const float val = o[ns][r] / l_i[r];
        Ob[((size_t)(b * S_LEN + qg)) * EMB + hh * HD + ns * 16 + lr] = f2bf(val);
      }
  }
}

// ---------------- output projection (LDS-staged A) ----------------
__global__ __launch_bounds__(256) void k_oproj(
    const unsigned short* __restrict__ Ob,
    const unsigned short* __restrict__ Wot,
    const float* __restrict__ bo,
    float* __restrict__ out) {
  __shared__ __attribute__((aligned(16))) unsigned short La[128 * 72];

  const int tid = threadIdx.x;
  const int lane = tid & 63;
  const int w = tid >> 6;
  const int wr = w >> 1, wc = w & 1;
  const int lr = lane & 15, lg = lane >> 4;
  const int m0 = blockIdx.x * 128;
  const int n0 = blockIdx.y * 128;

  const int srow = tid >> 3;
  const int sg = tid & 7;

  f32x4 acc[4][4] = {};
  short8 st[4];
#pragma unroll
  for (int i = 0; i < 4; ++i)
    st[i] = *reinterpret_cast<const short8*>(
        Ob + (size_t)(m0 + i * 32 + srow) * EMB + sg * 8);

  for (int kt = 0; kt < 6; ++kt) {
    __syncthreads();
#pragma unroll
    for (int i = 0; i < 4; ++i)
      *reinterpret_cast<short8*>(&La[(i * 32 + srow) * 72 + sg * 8]) = st[i];
    __syncthreads();
    if (kt < 5) {
      const int kn = (kt + 1) * 64;
#pragma unroll
      for (int i = 0; i < 4; ++i)
        st[i] = *reinterpret_cast<const short8*>(
            Ob + (size_t)(m0 + i * 32 + srow) * EMB + kn + sg * 8);
    }
#pragma unroll
    for (int kk = 0; kk < 2; ++kk) {
      short8 a[4], b[4];
#pragma unroll
      for (int ms = 0; ms < 4; ++ms)
        a[ms] = *reinterpret_cast<const short8*>(
            &La[(wr * 64 + ms * 16 + lr) * 72 + kk * 32 + lg * 8]);
#pragma unroll
      for (int ns = 0; ns < 4; ++ns)
        b[ns] = *reinterpret_cast<const short8*>(
            Wot + (size_t)(n0 + wc * 64 + ns * 16 + lr) * EMB + kt * 64 + kk * 32 + lg * 8);
#pragma unroll
      for (int ms = 0; ms < 4; ++ms)
#pragma unroll
        for (int ns = 0; ns < 4; ++ns)
          acc[ms][ns] = __builtin_amdgcn_mfma_f32_16x16x32_bf16(
              a[ms], b[ns], acc[ms][ns], 0, 0, 0);
    }
  }

#pragma unroll
  for (int ms = 0; ms < 4; ++ms)
#pragma unroll
    for (int ns = 0; ns < 4; ++ns)
#pragma unroll
      for (int r = 0; r < 4; ++r) {
        const int m = m0 + wr * 64 + ms * 16 + lg * 4 + r;
        const int n = n0 + wc * 64 + ns * 16 + lr;
        out[(size_t)m * EMB + n] = acc[ms][ns][r] + bo[n];
      }
}

// ---------------- launcher ----------------
extern "C" void kernel_launch(void* const* d_in, const int* in_sizes, int n_in,
                              void* d_out, int out_size, void* d_ws, size_t ws_size,
                              hipStream_t stream) {
  const float* x  = (const float*)d_in[0];
  const float* Wq = (const float*)d_in[1];
  const float* Wk = (const float*)d_in[2];
  const float* Wv = (const float*)d_in[3];
  const float* Wo = (const float*)d_in[4];
  const float* bo = (const float*)d_in[5];
  float* out = (float*)d_out;

  uint8_t* ws = (uint8_t*)d_ws;
  unsigned short* xb  = (unsigned short*)(ws);                 // 12582912 B
  unsigned short* Wqt = (unsigned short*)(ws + 12582912);
  unsigned short* Wkt = (unsigned short*)(ws + 12877824);
  unsigned short* Wvt = (unsigned short*)(ws + 13172736);
  unsigned short* Wot = (unsigned short*)(ws + 13467648);
  unsigned short* Qb  = (unsigned short*)(ws + 13762560);
  unsigned short* Kb  = (unsigned short*)(ws + 26345472);
  unsigned short* VT  = (unsigned short*)(ws + 38928384);      // [b,h,d,s]
  unsigned short* Ob  = (unsigned short*)(ws + 51511296);      // end 64094208

  hipLaunchKernelGGL(k_prep, dim3(3840), dim3(256), 0, stream,
                     x, xb, Wq, Wk, Wv, Wo, Wqt, Wkt, Wvt, Wot);
  hipLaunchKernelGGL(k_qkv, dim3(128, 9), dim3(256), 0, stream,
                     xb, Wqt, Wkt, Wvt, Qb, Kb, VT);
  hipLaunchKernelGGL(k_attn, dim3(16, 48), dim3(256), 0, stream, Qb, Kb, VT, Ob);
  hipLaunchKernelGGL(k_oproj, dim3(128, 3), dim3(256), 0, stream, Ob, Wot, bo, out);
}

// Round 5
// 215.505 us; speedup vs baseline: 2.2511x; 1.2309x over previous
//
#include <hip/hip_runtime.h>
#include <hip/hip_bf16.h>
#include <cstdint>
#include <cstddef>

typedef __attribute__((ext_vector_type(8))) short short8;
typedef __attribute__((ext_vector_type(4))) float f32x4;

#define S_LEN 2048
#define EMB 384
#define NH 6
#define HD 64
#define NB 8
// Q pre-scale: (1/sqrt(64)) * log2(e) so attn uses exp2 directly
#define QSCALE 0.180336880f

__device__ __forceinline__ unsigned short f2bf(float f) {
  unsigned u = __builtin_bit_cast(unsigned, f);
  u += 0x7fffu + ((u >> 16) & 1u);
  return (unsigned short)(u >> 16);
}

// ---------------- prep: x->bf16 and weight transpose+convert (fused) ----------------
__global__ __launch_bounds__(256) void k_prep(
    const float* __restrict__ x, unsigned short* __restrict__ xb,
    const float* __restrict__ Wq, const float* __restrict__ Wk,
    const float* __restrict__ Wv, const float* __restrict__ Wo,
    unsigned short* __restrict__ Wqt, unsigned short* __restrict__ Wkt,
    unsigned short* __restrict__ Wvt, unsigned short* __restrict__ Wot) {
  const int tid = threadIdx.x;
  if (blockIdx.x < 1536) {
    int i = blockIdx.x * 256 + tid;
    const int n4 = (NB * S_LEN * EMB) / 4;
    for (; i < n4; i += 1536 * 256) {
      const float4 v = reinterpret_cast<const float4*>(x)[i];
      ushort4 o;
      o.x = f2bf(v.x); o.y = f2bf(v.y); o.z = f2bf(v.z); o.w = f2bf(v.w);
      reinterpret_cast<ushort4*>(xb)[i] = o;
    }
  } else {
    const int idx = (blockIdx.x - 1536) * 256 + tid;  // 0..589823
    const int mat = idx / 147456;
    const int rem = idx - mat * 147456;
    const int k = rem / 384;
    const int n = rem - k * 384;
    const float* W = (mat == 0) ? Wq : (mat == 1) ? Wk : (mat == 2) ? Wv : Wo;
    unsigned short* Wt = (mat == 0) ? Wqt : (mat == 1) ? Wkt : (mat == 2) ? Wvt : Wot;
    Wt[n * 384 + k] = f2bf(W[rem]);
  }
}

// ---------------- fused QKV projection GEMM (LDS-staged A) ----------------
// grid (128, 9): y = wsel*3 + ngrp. Writes Q (pre-scaled), K, V all as [b,h,s,d].
__global__ __launch_bounds__(256) void k_qkv(
    const unsigned short* __restrict__ xb,
    const unsigned short* __restrict__ Wqt,
    const unsigned short* __restrict__ Wkt,
    const unsigned short* __restrict__ Wvt,
    unsigned short* __restrict__ Qb,
    unsigned short* __restrict__ Kb,
    unsigned short* __restrict__ Vb) {
  __shared__ __attribute__((aligned(16))) unsigned short La[128 * 72];  // A k-tile, pad 72

  const int tid = threadIdx.x;
  const int lane = tid & 63;
  const int w = tid >> 6;
  const int wr = w >> 1, wc = w & 1;
  const int lr = lane & 15, lg = lane >> 4;
  const int m0 = blockIdx.x * 128;
  const int wsel = blockIdx.y / 3;
  const int n0 = (blockIdx.y % 3) * 128;
  const unsigned short* Wt = (wsel == 0) ? Wqt : (wsel == 1) ? Wkt : Wvt;
  unsigned short* Out = (wsel == 0) ? Qb : (wsel == 1) ? Kb : Vb;

  const int srow = tid >> 3;       // 0..31
  const int sg = tid & 7;          // 16B slot

  f32x4 acc[4][4] = {};
  short8 st[4];
#pragma unroll
  for (int i = 0; i < 4; ++i)
    st[i] = *reinterpret_cast<const short8*>(
        xb + (size_t)(m0 + i * 32 + srow) * EMB + sg * 8);

  for (int kt = 0; kt < 6; ++kt) {
    __syncthreads();
#pragma unroll
    for (int i = 0; i < 4; ++i)
      *reinterpret_cast<short8*>(&La[(i * 32 + srow) * 72 + sg * 8]) = st[i];
    __syncthreads();
    if (kt < 5) {
      const int kn = (kt + 1) * 64;
#pragma unroll
      for (int i = 0; i < 4; ++i)
        st[i] = *reinterpret_cast<const short8*>(
            xb + (size_t)(m0 + i * 32 + srow) * EMB + kn + sg * 8);
    }
#pragma unroll
    for (int kk = 0; kk < 2; ++kk) {
      short8 a[4], b[4];
#pragma unroll
      for (int ms = 0; ms < 4; ++ms)
        a[ms] = *reinterpret_cast<const short8*>(
            &La[(wr * 64 + ms * 16 + lr) * 72 + kk * 32 + lg * 8]);
#pragma unroll
      for (int ns = 0; ns < 4; ++ns)
        b[ns] = *reinterpret_cast<const short8*>(
            Wt + (size_t)(n0 + wc * 64 + ns * 16 + lr) * EMB + kt * 64 + kk * 32 + lg * 8);
#pragma unroll
      for (int ms = 0; ms < 4; ++ms)
#pragma unroll
        for (int ns = 0; ns < 4; ++ns)
          acc[ms][ns] = __builtin_amdgcn_mfma_f32_16x16x32_bf16(
              a[ms], b[ns], acc[ms][ns], 0, 0, 0);
    }
  }

  const float sc = (wsel == 0) ? QSCALE : 1.0f;
#pragma unroll
  for (int ms = 0; ms < 4; ++ms)
#pragma unroll
    for (int ns = 0; ns < 4; ++ns)
#pragma unroll
      for (int r = 0; r < 4; ++r) {
        const int m = m0 + wr * 64 + ms * 16 + lg * 4 + r;  // b*S + s
        const int n = n0 + wc * 64 + ns * 16 + lr;          // h*D + d
        const int bb = m >> 11;
        const int s = m & 2047;
        const int h = n >> 6;
        const int d = n & 63;
        Out[(((size_t)bb * NH + h) * S_LEN + s) * HD + d] = f2bf(acc[ms][ns][r] * sc);
      }
}

// ---------------- V transpose: [b,h,s,d] -> [b,h,d,s] ----------------
__global__ __launch_bounds__(256) void k_vt(const unsigned short* __restrict__ Vb,
                                            unsigned short* __restrict__ Vtg) {
  __shared__ unsigned short L[64 * 65];
  const int tid = threadIdx.x;
  const int g = tid & 7;        // 16B chunk
  const int h = tid >> 3;       // 0..31
  const int st = blockIdx.x;    // s tile
  const int bh = blockIdx.y;
  const unsigned short* src = Vb + (size_t)bh * S_LEN * HD + (size_t)st * 64 * HD;
  unsigned short* dst = Vtg + (size_t)bh * S_LEN * HD;

#pragma unroll
  for (int c = 0; c < 2; ++c) {
    const int s = h + 32 * c;
    const short8 v = *reinterpret_cast<const short8*>(src + s * HD + g * 8);
#pragma unroll
    for (int j = 0; j < 8; ++j) L[s * 65 + g * 8 + j] = (unsigned short)v[j];
  }
  __syncthreads();
#pragma unroll
  for (int c = 0; c < 2; ++c) {
    const int d = h + 32 * c;
    short8 v;
#pragma unroll
    for (int j = 0; j < 8; ++j) v[j] = (short)L[(g * 8 + j) * 65 + d];
    *reinterpret_cast<short8*>(dst + (size_t)d * S_LEN + st * 64 + g * 8) = v;
  }
}

// ---------------- causal flash attention (KVBLK=64, swizzled LDS, no-max softmax) ----
// grid 768 XCD-swizzled; block 256 = 4 waves x 16 q-rows; q-tile 64, paired load-balance.
__global__ __launch_bounds__(256) void k_attn(
    const unsigned short* __restrict__ Qb,
    const unsigned short* __restrict__ Kb,
    const unsigned short* __restrict__ Vtg,
    unsigned short* __restrict__ Ob) {
  // all tiles [64][64] u16, unpadded; 16B-slot XOR swizzle: slot ^= row&7
  __shared__ __attribute__((aligned(16))) unsigned short Ks[64 * 64];
  __shared__ __attribute__((aligned(16))) unsigned short Vt[64 * 64];
  __shared__ __attribute__((aligned(16))) unsigned short Ps[64 * 64];

  const int tid = threadIdx.x;
  const int lane = tid & 63;
  const int w = tid >> 6;
  const int lr = lane & 15, lg = lane >> 4;

  // XCD swizzle: 768 blocks, 8 XCDs -> 96 consecutive per XCD (6 bh each, KV L2-resident)
  const int lin = blockIdx.y * 16 + blockIdx.x;
  const int swz = (lin & 7) * 96 + (lin >> 3);
  const int pair = swz & 15;
  const int bh = swz >> 4;

  const unsigned short* Qp = Qb + (size_t)bh * S_LEN * HD;
  const unsigned short* Kp = Kb + (size_t)bh * S_LEN * HD;
  const unsigned short* Vp = Vtg + (size_t)bh * S_LEN * HD;
  const int b = bh / NH, hh = bh - b * NH;

  const int srow = tid >> 3;       // 0..31 staging row
  const int sslot = tid & 7;       // 16B slot 0..7
  const int wsl0 = (sslot ^ (srow & 7)) << 3;        // swizzled u16 offset, rows srow & srow+32

  for (int phase = 0; phase < 2; ++phase) {
    const int qt = phase ? (31 - pair) : pair;
    const int qbase = qt * 64 + w * 16;

    const short8 aq0 = *reinterpret_cast<const short8*>(Qp + (size_t)(qbase + lr) * HD + lg * 8);
    const short8 aq1 = *reinterpret_cast<const short8*>(Qp + (size_t)(qbase + lr) * HD + 32 + lg * 8);

    f32x4 o[4] = {};
    float l_i[4] = {0.f, 0.f, 0.f, 0.f};

    // prefetch tile 0
    short8 pk0 = *reinterpret_cast<const short8*>(Kp + (size_t)srow * HD + sslot * 8);
    short8 pk1 = *reinterpret_cast<const short8*>(Kp + (size_t)(srow + 32) * HD + sslot * 8);
    short8 pv0 = *reinterpret_cast<const short8*>(Vp + (size_t)srow * S_LEN + sslot * 8);
    short8 pv1 = *reinterpret_cast<const short8*>(Vp + (size_t)(srow + 32) * S_LEN + sslot * 8);

    for (int t = 0; t <= qt; ++t) {
      __syncthreads();
      *reinterpret_cast<short8*>(&Ks[srow * 64 + wsl0]) = pk0;
      *reinterpret_cast<short8*>(&Ks[(srow + 32) * 64 + wsl0]) = pk1;
      *reinterpret_cast<short8*>(&Vt[srow * 64 + wsl0]) = pv0;
      *reinterpret_cast<short8*>(&Vt[(srow + 32) * 64 + wsl0]) = pv1;
      __syncthreads();

      if (t < qt) {
        const int tn = (t + 1) * 64;
        pk0 = *reinterpret_cast<const short8*>(Kp + (size_t)(tn + srow) * HD + sslot * 8);
        pk1 = *reinterpret_cast<const short8*>(Kp + (size_t)(tn + srow + 32) * HD + sslot * 8);
        pv0 = *reinterpret_cast<const short8*>(Vp + (size_t)srow * S_LEN + tn + sslot * 8);
        pv1 = *reinterpret_cast<const short8*>(Vp + (size_t)(srow + 32) * S_LEN + tn + sslot * 8);
      }

      // scores (Q pre-scaled to log2 units)
      float sv[4][4];
#pragma unroll
      for (int ks = 0; ks < 4; ++ks) {
        const int kstart = t * 64 + ks * 16;
        if (kstart > qbase + 15) {
#pragma unroll
          for (int r = 0; r < 4; ++r) sv[ks][r] = -1e30f;
        } else {
          const int krow = ks * 16 + lr;
          const int kx = krow & 7;
          const short8 bk0 = *reinterpret_cast<const short8*>(&Ks[krow * 64 + ((lg ^ kx) << 3)]);
          const short8 bk1 = *reinterpret_cast<const short8*>(&Ks[krow * 64 + (((4 + lg) ^ kx) << 3)]);
          f32x4 s = {};
          s = __builtin_amdgcn_mfma_f32_16x16x32_bf16(aq0, bk0, s, 0, 0, 0);
          s = __builtin_amdgcn_mfma_f32_16x16x32_bf16(aq1, bk1, s, 0, 0, 0);
          if (kstart + 15 <= qbase) {
#pragma unroll
            for (int r = 0; r < 4; ++r) sv[ks][r] = s[r];
          } else {
            const int kg = kstart + lr;
#pragma unroll
            for (int r = 0; r < 4; ++r)
              sv[ks][r] = (kg <= qbase + lg * 4 + r) ? s[r] : -1e30f;
          }
        }
      }

      // no-max softmax: p = exp2(s); lane-local l partials; P -> swizzled LDS
#pragma unroll
      for (int r = 0; r < 4; ++r) {
        const int q = w * 16 + lg * 4 + r;
        const int qx = q & 7;
        const int abase = q * 64 + (lr & 7);
        const int sp = lr >> 3;
        float p[4];
#pragma unroll
        for (int ks = 0; ks < 4; ++ks) p[ks] = __builtin_amdgcn_exp2f(sv[ks][r]);
        l_i[r] += (p[0] + p[1]) + (p[2] + p[3]);
#pragma unroll
        for (int ks = 0; ks < 4; ++ks)
          Ps[abase + ((((ks << 1) | sp) ^ qx) << 3)] = f2bf(p[ks]);
      }

      // PV: A = P[q][kv] (wave-local rows), B = V^T[d][kv]
      const int qrow = w * 16 + lr;
      const int qx2 = qrow & 7;
#pragma unroll
      for (int kk = 0; kk < 2; ++kk) {
        const short8 ap = *reinterpret_cast<const short8*>(
            &Ps[qrow * 64 + (((kk * 4 + lg) ^ qx2) << 3)]);
#pragma unroll
        for (int ns = 0; ns < 4; ++ns) {
          const int vrow = ns * 16 + lr;
          const short8 bv = *reinterpret_cast<const short8*>(
              &Vt[vrow * 64 + (((kk * 4 + lg) ^ (vrow & 7)) << 3)]);
          o[ns] = __builtin_amdgcn_mfma_f32_16x16x32_bf16(ap, bv, o[ns], 0, 0, 0);
        }
      }
    }

    // epilogue: reduce l across the 16 lr lanes, write O
#pragma unroll
    for (int r = 0; r < 4; ++r) {
      float l = l_i[r];
      l += __shfl_xor(l, 1);
      l += __shfl_xor(l, 2);
      l += __shfl_xor(l, 4);
      l += __shfl_xor(l, 8);
      l_i[r] = 1.0f / l;
    }
#pragma unroll
    for (int ns = 0; ns < 4; ++ns)
#pragma unroll
      for (int r = 0; r < 4; ++r) {
        const int qg = qbase + lg * 4 + r;
        const float val = o[ns][r] * l_i[r];
        Ob[((size_t)(b * S_LEN + qg)) * EMB + hh * HD + ns * 16 + lr] = f2bf(val);
      }
  }
}

// ---------------- output projection (LDS-staged A) ----------------
__global__ __launch_bounds__(256) void k_oproj(
    const unsigned short* __restrict__ Ob,
    const unsigned short* __restrict__ Wot,
    const float* __restrict__ bo,
    float* __restrict__ out) {
  __shared__ __attribute__((aligned(16))) unsigned short La[128 * 72];

  const int tid = threadIdx.x;
  const int lane = tid & 63;
  const int w = tid >> 6;
  const int wr = w >> 1, wc = w & 1;
  const int lr = lane & 15, lg = lane >> 4;
  const int m0 = blockIdx.x * 128;
  const int n0 = blockIdx.y * 128;

  const int srow = tid >> 3;
  const int sg = tid & 7;

  f32x4 acc[4][4] = {};
  short8 st[4];
#pragma unroll
  for (int i = 0; i < 4; ++i)
    st[i] = *reinterpret_cast<const short8*>(
        Ob + (size_t)(m0 + i * 32 + srow) * EMB + sg * 8);

  for (int kt = 0; kt < 6; ++kt) {
    __syncthreads();
#pragma unroll
    for (int i = 0; i < 4; ++i)
      *reinterpret_cast<short8*>(&La[(i * 32 + srow) * 72 + sg * 8]) = st[i];
    __syncthreads();
    if (kt < 5) {
      const int kn = (kt + 1) * 64;
#pragma unroll
      for (int i = 0; i < 4; ++i)
        st[i] = *reinterpret_cast<const short8*>(
            Ob + (size_t)(m0 + i * 32 + srow) * EMB + kn + sg * 8);
    }
#pragma unroll
    for (int kk = 0; kk < 2; ++kk) {
      short8 a[4], b[4];
#pragma unroll
      for (int ms = 0; ms < 4; ++ms)
        a[ms] = *reinterpret_cast<const short8*>(
            &La[(wr * 64 + ms * 16 + lr) * 72 + kk * 32 + lg * 8]);
#pragma unroll
      for (int ns = 0; ns < 4; ++ns)
        b[ns] = *reinterpret_cast<const short8*>(
            Wot + (size_t)(n0 + wc * 64 + ns * 16 + lr) * EMB + kt * 64 + kk * 32 + lg * 8);
#pragma unroll
      for (int ms = 0; ms < 4; ++ms)
#pragma unroll
        for (int ns = 0; ns < 4; ++ns)
          acc[ms][ns] = __builtin_amdgcn_mfma_f32_16x16x32_bf16(
              a[ms], b[ns], acc[ms][ns], 0, 0, 0);
    }
  }

#pragma unroll
  for (int ms = 0; ms < 4; ++ms)
#pragma unroll
    for (int ns = 0; ns < 4; ++ns)
#pragma unroll
      for (int r = 0; r < 4; ++r) {
        const int m = m0 + wr * 64 + ms * 16 + lg * 4 + r;
        const int n = n0 + wc * 64 + ns * 16 + lr;
        out[(size_t)m * EMB + n] = acc[ms][ns][r] + bo[n];
      }
}

// ---------------- launcher ----------------
extern "C" void kernel_launch(void* const* d_in, const int* in_sizes, int n_in,
                              void* d_out, int out_size, void* d_ws, size_t ws_size,
                              hipStream_t stream) {
  const float* x  = (const float*)d_in[0];
  const float* Wq = (const float*)d_in[1];
  const float* Wk = (const float*)d_in[2];
  const float* Wv = (const float*)d_in[3];
  const float* Wo = (const float*)d_in[4];
  const float* bo = (const float*)d_in[5];
  float* out = (float*)d_out;

  uint8_t* ws = (uint8_t*)d_ws;
  unsigned short* xb  = (unsigned short*)(ws);                 // 12582912 B
  unsigned short* Wqt = (unsigned short*)(ws + 12582912);
  unsigned short* Wkt = (unsigned short*)(ws + 12877824);
  unsigned short* Wvt = (unsigned short*)(ws + 13172736);
  unsigned short* Wot = (unsigned short*)(ws + 13467648);
  unsigned short* Qb  = (unsigned short*)(ws + 13762560);
  unsigned short* Kb  = (unsigned short*)(ws + 26345472);
  unsigned short* Vb  = (unsigned short*)(ws + 38928384);
  unsigned short* Ob  = (unsigned short*)(ws + 51511296);      // end 64094208
  unsigned short* VT  = xb;  // xb dead after k_qkv; reuse for V^T [b,h,d,s]

  hipLaunchKernelGGL(k_prep, dim3(3840), dim3(256), 0, stream,
                     x, xb, Wq, Wk, Wv, Wo, Wqt, Wkt, Wvt, Wot);
  hipLaunchKernelGGL(k_qkv, dim3(128, 9), dim3(256), 0, stream,
                     xb, Wqt, Wkt, Wvt, Qb, Kb, Vb);
  hipLaunchKernelGGL(k_vt, dim3(S_LEN / 64, NB * NH), dim3(256), 0, stream, Vb, VT);
  hipLaunchKernelGGL(k_attn, dim3(16, 48), dim3(256), 0, stream, Qb, Kb, VT, Ob);
  hipLaunchKernelGGL(k_oproj, dim3(128, 3), dim3(256), 0, stream, Ob, Wot, bo, out);
}

// Round 6
// 201.754 us; speedup vs baseline: 2.4045x; 1.0682x over previous
//
#include <hip/hip_runtime.h>
#include <hip/hip_bf16.h>
#include <cstdint>
#include <cstddef>

typedef __attribute__((ext_vector_type(8))) short short8;
typedef __attribute__((ext_vector_type(4))) float f32x4;

#define S_LEN 2048
#define EMB 384
#define NH 6
#define HD 64
#define NB 8
// Q pre-scale: (1/sqrt(64)) * log2(e) so attn uses exp2 directly
#define QSCALE 0.180336880f

__device__ __forceinline__ unsigned short f2bf(float f) {
  return __builtin_bit_cast(unsigned short, __float2bfloat16(f));
}

// ---------------- prep: x->bf16 (grid-stride) + coalesced LDS W-transpose ----------------
__global__ __launch_bounds__(256) void k_prep(
    const float* __restrict__ x, unsigned short* __restrict__ xb,
    const float* __restrict__ Wq, const float* __restrict__ Wk,
    const float* __restrict__ Wv, const float* __restrict__ Wo,
    unsigned short* __restrict__ Wqt, unsigned short* __restrict__ Wkt,
    unsigned short* __restrict__ Wvt, unsigned short* __restrict__ Wot) {
  const int tid = threadIdx.x;
  if (blockIdx.x < 1536) {
    int i = blockIdx.x * 256 + tid;
    const int n4 = (NB * S_LEN * EMB) / 4;
    for (; i < n4; i += 1536 * 256) {
      const float4 v = reinterpret_cast<const float4*>(x)[i];
      ushort4 o;
      o.x = f2bf(v.x); o.y = f2bf(v.y); o.z = f2bf(v.z); o.w = f2bf(v.w);
      reinterpret_cast<ushort4*>(xb)[i] = o;
    }
  } else {
    // W transpose: 4 mats x 36 tiles of 64x64, via LDS (coalesced in and out)
    __shared__ unsigned short Lw[64 * 66];
    const int bx2 = blockIdx.x - 1536;     // 0..143
    const int mat = bx2 / 36;
    const int tile = bx2 - mat * 36;
    const int k0 = (tile / 6) * 64;
    const int n0 = (tile % 6) * 64;
    const float* W = (mat == 0) ? Wq : (mat == 1) ? Wk : (mat == 2) ? Wv : Wo;
    unsigned short* Wt = (mat == 0) ? Wqt : (mat == 1) ? Wkt : (mat == 2) ? Wvt : Wot;
    const int f4 = tid & 15;
#pragma unroll
    for (int it = 0; it < 4; ++it) {
      const int kl = it * 16 + (tid >> 4);
      const float4 v = reinterpret_cast<const float4*>(W + (size_t)(k0 + kl) * EMB + n0)[f4];
      Lw[kl * 66 + f4 * 4 + 0] = f2bf(v.x);
      Lw[kl * 66 + f4 * 4 + 1] = f2bf(v.y);
      Lw[kl * 66 + f4 * 4 + 2] = f2bf(v.z);
      Lw[kl * 66 + f4 * 4 + 3] = f2bf(v.w);
    }
    __syncthreads();
    const int g = tid & 7;
#pragma unroll
    for (int it = 0; it < 2; ++it) {
      const int nl = it * 32 + (tid >> 3);
      short8 o;
#pragma unroll
      for (int j = 0; j < 8; ++j) o[j] = (short)Lw[(g * 8 + j) * 66 + nl];
      *reinterpret_cast<short8*>(Wt + (size_t)(n0 + nl) * EMB + k0 + g * 8) = o;
    }
  }
}

// ---------------- fused QKV projection GEMM (LDS A + full B/A prefetch) ----------------
// grid (128, 9): y = wsel*3 + ngrp. Q (pre-scaled), K as [b,h,s,d]; V directly as [b,h,d,s].
__global__ __launch_bounds__(256) void k_qkv(
    const unsigned short* __restrict__ xb,
    const unsigned short* __restrict__ Wqt,
    const unsigned short* __restrict__ Wkt,
    const unsigned short* __restrict__ Wvt,
    unsigned short* __restrict__ Qb,
    unsigned short* __restrict__ Kb,
    unsigned short* __restrict__ Vtb) {
  __shared__ __attribute__((aligned(16))) unsigned short La[128 * 72];   // A k-tile, pad 72
  __shared__ __attribute__((aligned(16))) unsigned short Lt[64 * 136];   // V^T repack

  const int tid = threadIdx.x;
  const int lane = tid & 63;
  const int w = tid >> 6;
  const int wr = w >> 1, wc = w & 1;
  const int lr = lane & 15, lg = lane >> 4;
  const int m0 = blockIdx.x * 128;
  const int wsel = blockIdx.y / 3;
  const int n0 = (blockIdx.y % 3) * 128;
  const unsigned short* Wt = (wsel == 0) ? Wqt : (wsel == 1) ? Wkt : Wvt;

  const int srow = tid >> 3;       // 0..31
  const int sg = tid & 7;          // 16B slot

  f32x4 acc[4][4] = {};
  short8 st[4];
  short8 breg[2][2][4];            // [parity][kk][frag]

  // prologue: tile 0 A + B
#pragma unroll
  for (int i = 0; i < 4; ++i)
    st[i] = *reinterpret_cast<const short8*>(
        xb + (size_t)(m0 + i * 32 + srow) * EMB + sg * 8);
#pragma unroll
  for (int kk = 0; kk < 2; ++kk)
#pragma unroll
    for (int ns = 0; ns < 4; ++ns)
      breg[0][kk][ns] = *reinterpret_cast<const short8*>(
          Wt + (size_t)(n0 + wc * 64 + ns * 16 + lr) * EMB + kk * 32 + lg * 8);

#pragma unroll
  for (int kt = 0; kt < 6; ++kt) {
    const int cur = kt & 1, nxt = cur ^ 1;
    __syncthreads();
#pragma unroll
    for (int i = 0; i < 4; ++i)
      *reinterpret_cast<short8*>(&La[(i * 32 + srow) * 72 + sg * 8]) = st[i];
    __syncthreads();
    if (kt < 5) {
      const int kn = (kt + 1) * 64;
#pragma unroll
      for (int i = 0; i < 4; ++i)
        st[i] = *reinterpret_cast<const short8*>(
            xb + (size_t)(m0 + i * 32 + srow) * EMB + kn + sg * 8);
#pragma unroll
      for (int kk = 0; kk < 2; ++kk)
#pragma unroll
        for (int ns = 0; ns < 4; ++ns)
          breg[nxt][kk][ns] = *reinterpret_cast<const short8*>(
              Wt + (size_t)(n0 + wc * 64 + ns * 16 + lr) * EMB + kn + kk * 32 + lg * 8);
    }
#pragma unroll
    for (int kk = 0; kk < 2; ++kk) {
      short8 a[4];
#pragma unroll
      for (int ms = 0; ms < 4; ++ms)
        a[ms] = *reinterpret_cast<const short8*>(
            &La[(wr * 64 + ms * 16 + lr) * 72 + kk * 32 + lg * 8]);
#pragma unroll
      for (int ms = 0; ms < 4; ++ms)
#pragma unroll
        for (int ns = 0; ns < 4; ++ns)
          acc[ms][ns] = __builtin_amdgcn_mfma_f32_16x16x32_bf16(
              a[ms], breg[cur][kk][ns], acc[ms][ns], 0, 0, 0);
    }
  }

  if (wsel != 2) {
    unsigned short* Out = (wsel == 0) ? Qb : Kb;
    const float sc = (wsel == 0) ? QSCALE : 1.0f;
#pragma unroll
    for (int ms = 0; ms < 4; ++ms)
#pragma unroll
      for (int ns = 0; ns < 4; ++ns)
#pragma unroll
        for (int r = 0; r < 4; ++r) {
          const int m = m0 + wr * 64 + ms * 16 + lg * 4 + r;  // b*S + s
          const int n = n0 + wc * 64 + ns * 16 + lr;          // h*D + d
          const int bb = m >> 11;
          const int s = m & 2047;
          const int h = n >> 6;
          const int d = n & 63;
          Out[(((size_t)bb * NH + h) * S_LEN + s) * HD + d] = f2bf(acc[ms][ns][r] * sc);
        }
  } else {
    // V: repack via LDS -> coalesced transposed store [b,h,d,s]
    const int bb = m0 >> 11;
    const int s0 = m0 & 2047;
#pragma unroll
    for (int p = 0; p < 2; ++p) {
      __syncthreads();
      if (wc == p) {
#pragma unroll
        for (int ms = 0; ms < 4; ++ms)
#pragma unroll
          for (int ns = 0; ns < 4; ++ns)
#pragma unroll
            for (int r = 0; r < 4; ++r) {
              const int dl = ns * 16 + lr;                     // d 0..63
              const int ml = wr * 64 + ms * 16 + lg * 4 + r;   // m 0..127
              Lt[dl * 136 + (((ml >> 3) ^ (dl & 7)) << 3) + (ml & 7)] = f2bf(acc[ms][ns][r]);
            }
      }
      __syncthreads();
      const int hg = 2 * (blockIdx.y % 3) + p;
      const int c = tid & 15;
#pragma unroll
      for (int it = 0; it < 4; ++it) {
        const int d = it * 16 + (tid >> 4);
        const short8 v = *reinterpret_cast<const short8*>(
            &Lt[d * 136 + ((c ^ (d & 7)) << 3)]);
        *reinterpret_cast<short8*>(
            Vtb + (((size_t)bb * NH + hg) * HD + d) * S_LEN + s0 + c * 8) = v;
      }
    }
  }
}

// ---------------- causal flash attention (KVBLK=64, swizzled LDS, no-max softmax) ----
// grid 1536: 1 q-tile per block, heavy-first per XCD group; 4 waves x 16 q-rows.
__global__ __launch_bounds__(256) void k_attn(
    const unsigned short* __restrict__ Qb,
    const unsigned short* __restrict__ Kb,
    const unsigned short* __restrict__ Vtg,
    unsigned short* __restrict__ Ob) {
  __shared__ __attribute__((aligned(16))) unsigned short Ks[64 * 64];
  __shared__ __attribute__((aligned(16))) unsigned short Vt[64 * 64];
  __shared__ __attribute__((aligned(16))) unsigned short Ps[64 * 64];

  const int tid = threadIdx.x;
  const int lane = tid & 63;
  const int w = tid >> 6;
  const int lr = lane & 15, lg = lane >> 4;

  // XCD mapping: 1536 blocks, xcd = lin&7 gets 192 consecutive work items
  // (6 bh, 32 q-tiles each, heavy qt first for load balance).
  const int lin = blockIdx.x;
  const int idx = lin >> 3;
  const int bh = (lin & 7) * 6 + (idx >> 5);
  const int qt = 31 - (idx & 31);

  const unsigned short* Qp = Qb + (size_t)bh * S_LEN * HD;
  const unsigned short* Kp = Kb + (size_t)bh * S_LEN * HD;
  const unsigned short* Vp = Vtg + (size_t)bh * S_LEN * HD;
  const int b = bh / NH, hh = bh - b * NH;

  const int srow = tid >> 3;       // 0..31 staging row
  const int sslot = tid & 7;       // 16B slot
  const int wsl0 = (sslot ^ (srow & 7)) << 3;

  const int qbase = qt * 64 + w * 16;

  const short8 aq0 = *reinterpret_cast<const short8*>(Qp + (size_t)(qbase + lr) * HD + lg * 8);
  const short8 aq1 = *reinterpret_cast<const short8*>(Qp + (size_t)(qbase + lr) * HD + 32 + lg * 8);

  f32x4 o[4] = {};
  float l_i[4] = {0.f, 0.f, 0.f, 0.f};

  short8 pk0 = *reinterpret_cast<const short8*>(Kp + (size_t)srow * HD + sslot * 8);
  short8 pk1 = *reinterpret_cast<const short8*>(Kp + (size_t)(srow + 32) * HD + sslot * 8);
  short8 pv0 = *reinterpret_cast<const short8*>(Vp + (size_t)srow * S_LEN + sslot * 8);
  short8 pv1 = *reinterpret_cast<const short8*>(Vp + (size_t)(srow + 32) * S_LEN + sslot * 8);

  for (int t = 0; t <= qt; ++t) {
    __syncthreads();
    *reinterpret_cast<short8*>(&Ks[srow * 64 + wsl0]) = pk0;
    *reinterpret_cast<short8*>(&Ks[(srow + 32) * 64 + wsl0]) = pk1;
    *reinterpret_cast<short8*>(&Vt[srow * 64 + wsl0]) = pv0;
    *reinterpret_cast<short8*>(&Vt[(srow + 32) * 64 + wsl0]) = pv1;
    __syncthreads();

    if (t < qt) {
      const int tn = (t + 1) * 64;
      pk0 = *reinterpret_cast<const short8*>(Kp + (size_t)(tn + srow) * HD + sslot * 8);
      pk1 = *reinterpret_cast<const short8*>(Kp + (size_t)(tn + srow + 32) * HD + sslot * 8);
      pv0 = *reinterpret_cast<const short8*>(Vp + (size_t)srow * S_LEN + tn + sslot * 8);
      pv1 = *reinterpret_cast<const short8*>(Vp + (size_t)(srow + 32) * S_LEN + tn + sslot * 8);
    }

    // scores (Q pre-scaled to log2 units)
    float sv[4][4];
    __builtin_amdgcn_s_setprio(1);
#pragma unroll
    for (int ks = 0; ks < 4; ++ks) {
      const int kstart = t * 64 + ks * 16;
      if (kstart > qbase + 15) {
#pragma unroll
        for (int r = 0; r < 4; ++r) sv[ks][r] = -1e30f;
      } else {
        const int krow = ks * 16 + lr;
        const int kx = krow & 7;
        const short8 bk0 = *reinterpret_cast<const short8*>(&Ks[krow * 64 + ((lg ^ kx) << 3)]);
        const short8 bk1 = *reinterpret_cast<const short8*>(&Ks[krow * 64 + (((4 + lg) ^ kx) << 3)]);
        f32x4 s = {};
        s = __builtin_amdgcn_mfma_f32_16x16x32_bf16(aq0, bk0, s, 0, 0, 0);
        s = __builtin_amdgcn_mfma_f32_16x16x32_bf16(aq1, bk1, s, 0, 0, 0);
        if (kstart + 15 <= qbase) {
#pragma unroll
          for (int r = 0; r < 4; ++r) sv[ks][r] = s[r];
        } else {
          const int kg = kstart + lr;
#pragma unroll
          for (int r = 0; r < 4; ++r)
            sv[ks][r] = (kg <= qbase + lg * 4 + r) ? s[r] : -1e30f;
        }
      }
    }
    __builtin_amdgcn_s_setprio(0);

    // no-max softmax: p = exp2(s); lane-local l partials; P -> swizzled LDS
#pragma unroll
    for (int r = 0; r < 4; ++r) {
      const int q = w * 16 + lg * 4 + r;
      const int qx = q & 7;
      const int abase = q * 64 + (lr & 7);
      const int sp = lr >> 3;
      float p[4];
#pragma unroll
      for (int ks = 0; ks < 4; ++ks) p[ks] = __builtin_amdgcn_exp2f(sv[ks][r]);
      l_i[r] += (p[0] + p[1]) + (p[2] + p[3]);
#pragma unroll
      for (int ks = 0; ks < 4; ++ks)
        Ps[abase + ((((ks << 1) | sp) ^ qx) << 3)] = f2bf(p[ks]);
    }

    // PV: A = P[q][kv] (wave-local rows), B = V^T[d][kv]
    const int qrow = w * 16 + lr;
    const int qx2 = qrow & 7;
    __builtin_amdgcn_s_setprio(1);
#pragma unroll
    for (int kk = 0; kk < 2; ++kk) {
      const short8 ap = *reinterpret_cast<const short8*>(
          &Ps[qrow * 64 + (((kk * 4 + lg) ^ qx2) << 3)]);
#pragma unroll
      for (int ns = 0; ns < 4; ++ns) {
        const int vrow = ns * 16 + lr;
        const short8 bv = *reinterpret_cast<const short8*>(
            &Vt[vrow * 64 + (((kk * 4 + lg) ^ (vrow & 7)) << 3)]);
        o[ns] = __builtin_amdgcn_mfma_f32_16x16x32_bf16(ap, bv, o[ns], 0, 0, 0);
      }
    }
    __builtin_amdgcn_s_setprio(0);
  }

  // epilogue: reduce l across the 16 lr lanes, write O
#pragma unroll
  for (int r = 0; r < 4; ++r) {
    float l = l_i[r];
    l += __shfl_xor(l, 1);
    l += __shfl_xor(l, 2);
    l += __shfl_xor(l, 4);
    l += __shfl_xor(l, 8);
    l_i[r] = 1.0f / l;
  }
#pragma unroll
  for (int ns = 0; ns < 4; ++ns)
#pragma unroll
    for (int r = 0; r < 4; ++r) {
      const int qg = qbase + lg * 4 + r;
      const float val = o[ns][r] * l_i[r];
      Ob[((size_t)(b * S_LEN + qg)) * EMB + hh * HD + ns * 16 + lr] = f2bf(val);
    }
}

// ---------------- output projection (LDS A + full B/A prefetch) ----------------
__global__ __launch_bounds__(256) void k_oproj(
    const unsigned short* __restrict__ Ob,
    const unsigned short* __restrict__ Wot,
    const float* __restrict__ bo,
    float* __restrict__ out) {
  __shared__ __attribute__((aligned(16))) unsigned short La[128 * 72];

  const int tid = threadIdx.x;
  const int lane = tid & 63;
  const int w = tid >> 6;
  const int wr = w >> 1, wc = w & 1;
  const int lr = lane & 15, lg = lane >> 4;
  const int m0 = blockIdx.x * 128;
  const int n0 = blockIdx.y * 128;

  const int srow = tid >> 3;
  const int sg = tid & 7;

  f32x4 acc[4][4] = {};
  short8 st[4];
  short8 breg[2][2][4];

#pragma unroll
  for (int i = 0; i < 4; ++i)
    st[i] = *reinterpret_cast<const short8*>(
        Ob + (size_t)(m0 + i * 32 + srow) * EMB + sg * 8);
#pragma unroll
  for (int kk = 0; kk < 2; ++kk)
#pragma unroll
    for (int ns = 0; ns < 4; ++ns)
      breg[0][kk][ns] = *reinterpret_cast<const short8*>(
          Wot + (size_t)(n0 + wc * 64 + ns * 16 + lr) * EMB + kk * 32 + lg * 8);

#pragma unroll
  for (int kt = 0; kt < 6; ++kt) {
    const int cur = kt & 1, nxt = cur ^ 1;
    __syncthreads();
#pragma unroll
    for (int i = 0; i < 4; ++i)
      *reinterpret_cast<short8*>(&La[(i * 32 + srow) * 72 + sg * 8]) = st[i];
    __syncthreads();
    if (kt < 5) {
      const int kn = (kt + 1) * 64;
#pragma unroll
      for (int i = 0; i < 4; ++i)
        st[i] = *reinterpret_cast<const short8*>(
            Ob + (size_t)(m0 + i * 32 + srow) * EMB + kn + sg * 8);
#pragma unroll
      for (int kk = 0; kk < 2; ++kk)
#pragma unroll
        for (int ns = 0; ns < 4; ++ns)
          breg[nxt][kk][ns] = *reinterpret_cast<const short8*>(
              Wot + (size_t)(n0 + wc * 64 + ns * 16 + lr) * EMB + kn + kk * 32 + lg * 8);
    }
#pragma unroll
    for (int kk = 0; kk < 2; ++kk) {
      short8 a[4];
#pragma unroll
      for (int ms = 0; ms < 4; ++ms)
        a[ms] = *reinterpret_cast<const short8*>(
            &La[(wr * 64 + ms * 16 + lr) * 72 + kk * 32 + lg * 8]);
#pragma unroll
      for (int ms = 0; ms < 4; ++ms)
#pragma unroll
        for (int ns = 0; ns < 4; ++ns)
          acc[ms][ns] = __builtin_amdgcn_mfma_f32_16x16x32_bf16(
              a[ms], breg[cur][kk][ns], acc[ms][ns], 0, 0, 0);
    }
  }

#pragma unroll
  for (int ms = 0; ms < 4; ++ms)
#pragma unroll
    for (int ns = 0; ns < 4; ++ns)
#pragma unroll
      for (int r = 0; r < 4; ++r) {
        const int m = m0 + wr * 64 + ms * 16 + lg * 4 + r;
        const int n = n0 + wc * 64 + ns * 16 + lr;
        out[(size_t)m * EMB + n] = acc[ms][ns][r] + bo[n];
      }
}

// ---------------- launcher ----------------
extern "C" void kernel_launch(void* const* d_in, const int* in_sizes, int n_in,
                              void* d_out, int out_size, void* d_ws, size_t ws_size,
                              hipStream_t stream) {
  const float* x  = (const float*)d_in[0];
  const float* Wq = (const float*)d_in[1];
  const float* Wk = (const float*)d_in[2];
  const float* Wv = (const float*)d_in[3];
  const float* Wo = (const float*)d_in[4];
  const float* bo = (const float*)d_in[5];
  float* out = (float*)d_out;

  uint8_t* ws = (uint8_t*)d_ws;
  unsigned short* xb  = (unsigned short*)(ws);                 // 12582912 B
  unsigned short* Wqt = (unsigned short*)(ws + 12582912);
  unsigned short* Wkt = (unsigned short*)(ws + 12877824);
  unsigned short* Wvt = (unsigned short*)(ws + 13172736);
  unsigned short* Wot = (unsigned short*)(ws + 13467648);
  unsigned short* Qb  = (unsigned short*)(ws + 13762560);
  unsigned short* Kb  = (unsigned short*)(ws + 26345472);
  unsigned short* VT  = (unsigned short*)(ws + 38928384);      // [b,h,d,s]
  unsigned short* Ob  = (unsigned short*)(ws + 51511296);      // end 64094208

  hipLaunchKernelGGL(k_prep, dim3(1680), dim3(256), 0, stream,
                     x, xb, Wq, Wk, Wv, Wo, Wqt, Wkt, Wvt, Wot);
  hipLaunchKernelGGL(k_qkv, dim3(128, 9), dim3(256), 0, stream,
                     xb, Wqt, Wkt, Wvt, Qb, Kb, VT);
  hipLaunchKernelGGL(k_attn, dim3(1536), dim3(256), 0, stream, Qb, Kb, VT, Ob);
  hipLaunchKernelGGL(k_oproj, dim3(128, 3), dim3(256), 0, stream, Ob, Wot, bo, out);
}

// Round 7
// 197.839 us; speedup vs baseline: 2.4521x; 1.0198x over previous
//
#include <hip/hip_runtime.h>
#include <hip/hip_bf16.h>
#include <cstdint>
#include <cstddef>

typedef __attribute__((ext_vector_type(8))) short short8;
typedef __attribute__((ext_vector_type(4))) float f32x4;

#define S_LEN 2048
#define EMB 384
#define NH 6
#define HD 64
#define NB 8
// Q pre-scale: (1/sqrt(64)) * log2(e) so attn uses exp2 directly
#define QSCALE 0.180336880f

__device__ __forceinline__ unsigned short f2bf(float f) {
  return __builtin_bit_cast(unsigned short, __float2bfloat16(f));
}

// ---------------- prep: x->bf16 (grid-stride) + coalesced LDS W-transpose ----------------
__global__ __launch_bounds__(256) void k_prep(
    const float* __restrict__ x, unsigned short* __restrict__ xb,
    const float* __restrict__ Wq, const float* __restrict__ Wk,
    const float* __restrict__ Wv, const float* __restrict__ Wo,
    unsigned short* __restrict__ Wqt, unsigned short* __restrict__ Wkt,
    unsigned short* __restrict__ Wvt, unsigned short* __restrict__ Wot) {
  const int tid = threadIdx.x;
  if (blockIdx.x < 1536) {
    int i = blockIdx.x * 256 + tid;
    const int n4 = (NB * S_LEN * EMB) / 4;
    for (; i < n4; i += 1536 * 256) {
      const float4 v = reinterpret_cast<const float4*>(x)[i];
      ushort4 o;
      o.x = f2bf(v.x); o.y = f2bf(v.y); o.z = f2bf(v.z); o.w = f2bf(v.w);
      reinterpret_cast<ushort4*>(xb)[i] = o;
    }
  } else {
    // W transpose: 4 mats x 36 tiles of 64x64, via LDS (coalesced in and out)
    __shared__ unsigned short Lw[64 * 66];
    const int bx2 = blockIdx.x - 1536;     // 0..143
    const int mat = bx2 / 36;
    const int tile = bx2 - mat * 36;
    const int k0 = (tile / 6) * 64;
    const int n0 = (tile % 6) * 64;
    const float* W = (mat == 0) ? Wq : (mat == 1) ? Wk : (mat == 2) ? Wv : Wo;
    unsigned short* Wt = (mat == 0) ? Wqt : (mat == 1) ? Wkt : (mat == 2) ? Wvt : Wot;
    const int f4 = tid & 15;
#pragma unroll
    for (int it = 0; it < 4; ++it) {
      const int kl = it * 16 + (tid >> 4);
      const float4 v = reinterpret_cast<const float4*>(W + (size_t)(k0 + kl) * EMB + n0)[f4];
      Lw[kl * 66 + f4 * 4 + 0] = f2bf(v.x);
      Lw[kl * 66 + f4 * 4 + 1] = f2bf(v.y);
      Lw[kl * 66 + f4 * 4 + 2] = f2bf(v.z);
      Lw[kl * 66 + f4 * 4 + 3] = f2bf(v.w);
    }
    __syncthreads();
    const int g = tid & 7;
#pragma unroll
    for (int it = 0; it < 2; ++it) {
      const int nl = it * 32 + (tid >> 3);
      short8 o;
#pragma unroll
      for (int j = 0; j < 8; ++j) o[j] = (short)Lw[(g * 8 + j) * 66 + nl];
      *reinterpret_cast<short8*>(Wt + (size_t)(n0 + nl) * EMB + k0 + g * 8) = o;
    }
  }
}

// ---------------- fused QKV projection GEMM (LDS A + B/A prefetch, XCD swizzle) --------
// 1152 blocks: xcd = bid&7 owns 16 consecutive m-tiles x all 9 (wsel,ngrp) -> xb L2-resident.
__global__ __launch_bounds__(256) void k_qkv(
    const unsigned short* __restrict__ xb,
    const unsigned short* __restrict__ Wqt,
    const unsigned short* __restrict__ Wkt,
    const unsigned short* __restrict__ Wvt,
    unsigned short* __restrict__ Qb,
    unsigned short* __restrict__ Kb,
    unsigned short* __restrict__ Vtb) {
  __shared__ __attribute__((aligned(16))) unsigned short La[128 * 72];   // A k-tile, pad 72
  __shared__ __attribute__((aligned(16))) unsigned short Lt[64 * 136];   // V^T repack

  const int tid = threadIdx.x;
  const int lane = tid & 63;
  const int w = tid >> 6;
  const int wr = w >> 1, wc = w & 1;
  const int lr = lane & 15, lg = lane >> 4;

  const int bid = blockIdx.y * 128 + blockIdx.x;
  const int xcd = bid & 7;
  const int pos = bid >> 3;            // 0..143
  const int bx = xcd * 16 + (pos & 15);
  const int by = pos >> 4;             // 0..8
  const int m0 = bx * 128;
  const int wsel = by / 3;
  const int n0 = (by % 3) * 128;
  const unsigned short* Wt = (wsel == 0) ? Wqt : (wsel == 1) ? Wkt : Wvt;

  const int srow = tid >> 3;       // 0..31
  const int sg = tid & 7;          // 16B slot

  f32x4 acc[4][4] = {};
  short8 st[4];
  short8 breg[2][2][4];            // [parity][kk][frag]

#pragma unroll
  for (int i = 0; i < 4; ++i)
    st[i] = *reinterpret_cast<const short8*>(
        xb + (size_t)(m0 + i * 32 + srow) * EMB + sg * 8);
#pragma unroll
  for (int kk = 0; kk < 2; ++kk)
#pragma unroll
    for (int ns = 0; ns < 4; ++ns)
      breg[0][kk][ns] = *reinterpret_cast<const short8*>(
          Wt + (size_t)(n0 + wc * 64 + ns * 16 + lr) * EMB + kk * 32 + lg * 8);

#pragma unroll
  for (int kt = 0; kt < 6; ++kt) {
    const int cur = kt & 1, nxt = cur ^ 1;
    __syncthreads();
#pragma unroll
    for (int i = 0; i < 4; ++i)
      *reinterpret_cast<short8*>(&La[(i * 32 + srow) * 72 + sg * 8]) = st[i];
    __syncthreads();
    if (kt < 5) {
      const int kn = (kt + 1) * 64;
#pragma unroll
      for (int i = 0; i < 4; ++i)
        st[i] = *reinterpret_cast<const short8*>(
            xb + (size_t)(m0 + i * 32 + srow) * EMB + kn + sg * 8);
#pragma unroll
      for (int kk = 0; kk < 2; ++kk)
#pragma unroll
        for (int ns = 0; ns < 4; ++ns)
          breg[nxt][kk][ns] = *reinterpret_cast<const short8*>(
              Wt + (size_t)(n0 + wc * 64 + ns * 16 + lr) * EMB + kn + kk * 32 + lg * 8);
    }
#pragma unroll
    for (int kk = 0; kk < 2; ++kk) {
      short8 a[4];
#pragma unroll
      for (int ms = 0; ms < 4; ++ms)
        a[ms] = *reinterpret_cast<const short8*>(
            &La[(wr * 64 + ms * 16 + lr) * 72 + kk * 32 + lg * 8]);
#pragma unroll
      for (int ms = 0; ms < 4; ++ms)
#pragma unroll
        for (int ns = 0; ns < 4; ++ns)
          acc[ms][ns] = __builtin_amdgcn_mfma_f32_16x16x32_bf16(
              a[ms], breg[cur][kk][ns], acc[ms][ns], 0, 0, 0);
    }
  }

  if (wsel != 2) {
    unsigned short* Out = (wsel == 0) ? Qb : Kb;
    const float sc = (wsel == 0) ? QSCALE : 1.0f;
#pragma unroll
    for (int ms = 0; ms < 4; ++ms)
#pragma unroll
      for (int ns = 0; ns < 4; ++ns)
#pragma unroll
        for (int r = 0; r < 4; ++r) {
          const int m = m0 + wr * 64 + ms * 16 + lg * 4 + r;  // b*S + s
          const int n = n0 + wc * 64 + ns * 16 + lr;          // h*D + d
          const int bb = m >> 11;
          const int s = m & 2047;
          const int h = n >> 6;
          const int d = n & 63;
          Out[(((size_t)bb * NH + h) * S_LEN + s) * HD + d] = f2bf(acc[ms][ns][r] * sc);
        }
  } else {
    // V: repack via LDS -> coalesced transposed store [b,h,d,s]
    const int bb = m0 >> 11;
    const int s0 = m0 & 2047;
#pragma unroll
    for (int p = 0; p < 2; ++p) {
      __syncthreads();
      if (wc == p) {
#pragma unroll
        for (int ms = 0; ms < 4; ++ms)
#pragma unroll
          for (int ns = 0; ns < 4; ++ns)
#pragma unroll
            for (int r = 0; r < 4; ++r) {
              const int dl = ns * 16 + lr;                     // d 0..63
              const int ml = wr * 64 + ms * 16 + lg * 4 + r;   // m 0..127
              Lt[dl * 136 + (((ml >> 3) ^ (dl & 7)) << 3) + (ml & 7)] = f2bf(acc[ms][ns][r]);
            }
      }
      __syncthreads();
      const int hg = 2 * (n0 >> 7) + p;
      const int c = tid & 15;
#pragma unroll
      for (int it = 0; it < 4; ++it) {
        const int d = it * 16 + (tid >> 4);
        const short8 v = *reinterpret_cast<const short8*>(
            &Lt[d * 136 + ((c ^ (d & 7)) << 3)]);
        *reinterpret_cast<short8*>(
            Vtb + (((size_t)bb * NH + hg) * HD + d) * S_LEN + s0 + c * 8) = v;
      }
    }
  }
}

// ---------------- causal flash attention (KVBLK=64, swizzled LDS, no-max softmax) ----
// grid 768 XCD-swizzled; block 256 = 4 waves x 16 q-rows; paired q-tiles (33 KV each).
__global__ __launch_bounds__(256) void k_attn(
    const unsigned short* __restrict__ Qb,
    const unsigned short* __restrict__ Kb,
    const unsigned short* __restrict__ Vtg,
    unsigned short* __restrict__ Ob) {
  __shared__ __attribute__((aligned(16))) unsigned short Ks[64 * 64];
  __shared__ __attribute__((aligned(16))) unsigned short Vt[64 * 64];
  __shared__ __attribute__((aligned(16))) unsigned short Ps[64 * 64];

  const int tid = threadIdx.x;
  const int lane = tid & 63;
  const int w = tid >> 6;
  const int lr = lane & 15, lg = lane >> 4;

  // XCD swizzle: 768 blocks, 8 XCDs -> 96 consecutive per XCD (6 bh each, KV L2-resident)
  const int lin = blockIdx.y * 16 + blockIdx.x;
  const int swz = (lin & 7) * 96 + (lin >> 3);
  const int pair = swz & 15;
  const int bh = swz >> 4;

  const unsigned short* Qp = Qb + (size_t)bh * S_LEN * HD;
  const unsigned short* Kp = Kb + (size_t)bh * S_LEN * HD;
  const unsigned short* Vp = Vtg + (size_t)bh * S_LEN * HD;
  const int b = bh / NH, hh = bh - b * NH;

  const int srow = tid >> 3;       // 0..31 staging row
  const int sslot = tid & 7;       // 16B slot
  const int wsl0 = (sslot ^ (srow & 7)) << 3;

  for (int phase = 0; phase < 2; ++phase) {
    const int qt = phase ? (31 - pair) : pair;
    const int qbase = qt * 64 + w * 16;

    const short8 aq0 = *reinterpret_cast<const short8*>(Qp + (size_t)(qbase + lr) * HD + lg * 8);
    const short8 aq1 = *reinterpret_cast<const short8*>(Qp + (size_t)(qbase + lr) * HD + 32 + lg * 8);

    f32x4 o[4] = {};
    float l_i[4] = {0.f, 0.f, 0.f, 0.f};

    short8 pk0 = *reinterpret_cast<const short8*>(Kp + (size_t)srow * HD + sslot * 8);
    short8 pk1 = *reinterpret_cast<const short8*>(Kp + (size_t)(srow + 32) * HD + sslot * 8);
    short8 pv0 = *reinterpret_cast<const short8*>(Vp + (size_t)srow * S_LEN + sslot * 8);
    short8 pv1 = *reinterpret_cast<const short8*>(Vp + (size_t)(srow + 32) * S_LEN + sslot * 8);

    for (int t = 0; t <= qt; ++t) {
      __syncthreads();
      *reinterpret_cast<short8*>(&Ks[srow * 64 + wsl0]) = pk0;
      *reinterpret_cast<short8*>(&Ks[(srow + 32) * 64 + wsl0]) = pk1;
      *reinterpret_cast<short8*>(&Vt[srow * 64 + wsl0]) = pv0;
      *reinterpret_cast<short8*>(&Vt[(srow + 32) * 64 + wsl0]) = pv1;
      __syncthreads();

      if (t < qt) {
        const int tn = (t + 1) * 64;
        pk0 = *reinterpret_cast<const short8*>(Kp + (size_t)(tn + srow) * HD + sslot * 8);
        pk1 = *reinterpret_cast<const short8*>(Kp + (size_t)(tn + srow + 32) * HD + sslot * 8);
        pv0 = *reinterpret_cast<const short8*>(Vp + (size_t)srow * S_LEN + tn + sslot * 8);
        pv1 = *reinterpret_cast<const short8*>(Vp + (size_t)(srow + 32) * S_LEN + tn + sslot * 8);
      }

      // scores (Q pre-scaled to log2 units)
      float sv[4][4];
#pragma unroll
      for (int ks = 0; ks < 4; ++ks) {
        const int kstart = t * 64 + ks * 16;
        if (kstart > qbase + 15) {
#pragma unroll
          for (int r = 0; r < 4; ++r) sv[ks][r] = -1e30f;
        } else {
          const int krow = ks * 16 + lr;
          const int kx = krow & 7;
          const short8 bk0 = *reinterpret_cast<const short8*>(&Ks[krow * 64 + ((lg ^ kx) << 3)]);
          const short8 bk1 = *reinterpret_cast<const short8*>(&Ks[krow * 64 + (((4 + lg) ^ kx) << 3)]);
          f32x4 s = {};
          s = __builtin_amdgcn_mfma_f32_16x16x32_bf16(aq0, bk0, s, 0, 0, 0);
          s = __builtin_amdgcn_mfma_f32_16x16x32_bf16(aq1, bk1, s, 0, 0, 0);
          if (kstart + 15 <= qbase) {
#pragma unroll
            for (int r = 0; r < 4; ++r) sv[ks][r] = s[r];
          } else {
            const int kg = kstart + lr;
#pragma unroll
            for (int r = 0; r < 4; ++r)
              sv[ks][r] = (kg <= qbase + lg * 4 + r) ? s[r] : -1e30f;
          }
        }
      }

      // no-max softmax: p = exp2(s); lane-local l partials; P -> swizzled LDS
#pragma unroll
      for (int r = 0; r < 4; ++r) {
        const int q = w * 16 + lg * 4 + r;
        const int qx = q & 7;
        const int abase = q * 64 + (lr & 7);
        const int sp = lr >> 3;
        float p[4];
#pragma unroll
        for (int ks = 0; ks < 4; ++ks) p[ks] = __builtin_amdgcn_exp2f(sv[ks][r]);
        l_i[r] += (p[0] + p[1]) + (p[2] + p[3]);
#pragma unroll
        for (int ks = 0; ks < 4; ++ks)
          Ps[abase + ((((ks << 1) | sp) ^ qx) << 3)] = f2bf(p[ks]);
      }

      // PV: A = P[q][kv] (wave-local rows), B = V^T[d][kv]
      const int qrow = w * 16 + lr;
      const int qx2 = qrow & 7;
#pragma unroll
      for (int kk = 0; kk < 2; ++kk) {
        const short8 ap = *reinterpret_cast<const short8*>(
            &Ps[qrow * 64 + (((kk * 4 + lg) ^ qx2) << 3)]);
#pragma unroll
        for (int ns = 0; ns < 4; ++ns) {
          const int vrow = ns * 16 + lr;
          const short8 bv = *reinterpret_cast<const short8*>(
              &Vt[vrow * 64 + (((kk * 4 + lg) ^ (vrow & 7)) << 3)]);
          o[ns] = __builtin_amdgcn_mfma_f32_16x16x32_bf16(ap, bv, o[ns], 0, 0, 0);
        }
      }
    }

    // epilogue: reduce l across the 16 lr lanes, write O
#pragma unroll
    for (int r = 0; r < 4; ++r) {
      float l = l_i[r];
      l += __shfl_xor(l, 1);
      l += __shfl_xor(l, 2);
      l += __shfl_xor(l, 4);
      l += __shfl_xor(l, 8);
      l_i[r] = 1.0f / l;
    }
#pragma unroll
    for (int ns = 0; ns < 4; ++ns)
#pragma unroll
      for (int r = 0; r < 4; ++r) {
        const int qg = qbase + lg * 4 + r;
        const float val = o[ns][r] * l_i[r];
        Ob[((size_t)(b * S_LEN + qg)) * EMB + hh * HD + ns * 16 + lr] = f2bf(val);
      }
  }
}

// ---------------- output projection (BM=64 retile -> 768 blocks, XCD swizzle) ---------
__global__ __launch_bounds__(256) void k_oproj(
    const unsigned short* __restrict__ Ob,
    const unsigned short* __restrict__ Wot,
    const float* __restrict__ bo,
    float* __restrict__ out) {
  __shared__ __attribute__((aligned(16))) unsigned short La[64 * 72];

  const int tid = threadIdx.x;
  const int lane = tid & 63;
  const int w = tid >> 6;
  const int lr = lane & 15, lg = lane >> 4;

  const int bid = blockIdx.y * 256 + blockIdx.x;
  const int xcd = bid & 7;
  const int pos = bid >> 3;            // 0..95
  const int m0 = (xcd * 32 + (pos & 31)) * 64;
  const int n0 = (pos >> 5) * 128;

  const int srow = tid >> 3;       // 0..31
  const int sg = tid & 7;

  f32x4 acc[4][2] = {};
  short8 st[2];
  short8 breg[2][2][2];            // [parity][kk][ns]

#pragma unroll
  for (int i = 0; i < 2; ++i)
    st[i] = *reinterpret_cast<const short8*>(
        Ob + (size_t)(m0 + i * 32 + srow) * EMB + sg * 8);
#pragma unroll
  for (int kk = 0; kk < 2; ++kk)
#pragma unroll
    for (int ns = 0; ns < 2; ++ns)
      breg[0][kk][ns] = *reinterpret_cast<const short8*>(
          Wot + (size_t)(n0 + w * 32 + ns * 16 + lr) * EMB + kk * 32 + lg * 8);

#pragma unroll
  for (int kt = 0; kt < 6; ++kt) {
    const int cur = kt & 1, nxt = cur ^ 1;
    __syncthreads();
#pragma unroll
    for (int i = 0; i < 2; ++i)
      *reinterpret_cast<short8*>(&La[(i * 32 + srow) * 72 + sg * 8]) = st[i];
    __syncthreads();
    if (kt < 5) {
      const int kn = (kt + 1) * 64;
#pragma unroll
      for (int i = 0; i < 2; ++i)
        st[i] = *reinterpret_cast<const short8*>(
            Ob + (size_t)(m0 + i * 32 + srow) * EMB + kn + sg * 8);
#pragma unroll
      for (int kk = 0; kk < 2; ++kk)
#pragma unroll
        for (int ns = 0; ns < 2; ++ns)
          breg[nxt][kk][ns] = *reinterpret_cast<const short8*>(
              Wot + (size_t)(n0 + w * 32 + ns * 16 + lr) * EMB + kn + kk * 32 + lg * 8);
    }
#pragma unroll
    for (int kk = 0; kk < 2; ++kk) {
      short8 a[4];
#pragma unroll
      for (int ms = 0; ms < 4; ++ms)
        a[ms] = *reinterpret_cast<const short8*>(
            &La[(ms * 16 + lr) * 72 + kk * 32 + lg * 8]);
#pragma unroll
      for (int ms = 0; ms < 4; ++ms)
#pragma unroll
        for (int ns = 0; ns < 2; ++ns)
          acc[ms][ns] = __builtin_amdgcn_mfma_f32_16x16x32_bf16(
              a[ms], breg[cur][kk][ns], acc[ms][ns], 0, 0, 0);
    }
  }

#pragma unroll
  for (int ms = 0; ms < 4; ++ms)
#pragma unroll
    for (int ns = 0; ns < 2; ++ns)
#pragma unroll
      for (int r = 0; r < 4; ++r) {
        const int m = m0 + ms * 16 + lg * 4 + r;
        const int n = n0 + w * 32 + ns * 16 + lr;
        out[(size_t)m * EMB + n] = acc[ms][ns][r] + bo[n];
      }
}

// ---------------- launcher ----------------
extern "C" void kernel_launch(void* const* d_in, const int* in_sizes, int n_in,
                              void* d_out, int out_size, void* d_ws, size_t ws_size,
                              hipStream_t stream) {
  const float* x  = (const float*)d_in[0];
  const float* Wq = (const float*)d_in[1];
  const float* Wk = (const float*)d_in[2];
  const float* Wv = (const float*)d_in[3];
  const float* Wo = (const float*)d_in[4];
  const float* bo = (const float*)d_in[5];
  float* out = (float*)d_out;

  uint8_t* ws = (uint8_t*)d_ws;
  unsigned short* xb  = (unsigned short*)(ws);                 // 12582912 B
  unsigned short* Wqt = (unsigned short*)(ws + 12582912);
  unsigned short* Wkt = (unsigned short*)(ws + 12877824);
  unsigned short* Wvt = (unsigned short*)(ws + 13172736);
  unsigned short* Wot = (unsigned short*)(ws + 13467648);
  unsigned short* Qb  = (unsigned short*)(ws + 13762560);
  unsigned short* Kb  = (unsigned short*)(ws + 26345472);
  unsigned short* VT  = (unsigned short*)(ws + 38928384);      // [b,h,d,s]
  unsigned short* Ob  = (unsigned short*)(ws + 51511296);      // end 64094208

  hipLaunchKernelGGL(k_prep, dim3(1680), dim3(256), 0, stream,
                     x, xb, Wq, Wk, Wv, Wo, Wqt, Wkt, Wvt, Wot);
  hipLaunchKernelGGL(k_qkv, dim3(128, 9), dim3(256), 0, stream,
                     xb, Wqt, Wkt, Wvt, Qb, Kb, VT);
  hipLaunchKernelGGL(k_attn, dim3(16, 48), dim3(256), 0, stream, Qb, Kb, VT, Ob);
  hipLaunchKernelGGL(k_oproj, dim3(256, 3), dim3(256), 0, stream, Ob, Wot, bo, out);
}